// Round 9
// baseline (1766.107 us; speedup 1.0000x reference)
//
#include <hip/hip_runtime.h>

#define V_N 50000
#define E_N 800000
#define H_N 128

typedef __bf16 bf16;
typedef bf16 bf16x4 __attribute__((ext_vector_type(4)));
typedef bf16 bf16x8 __attribute__((ext_vector_type(8)));
typedef float f32x4 __attribute__((ext_vector_type(4)));

// PQ all-bf16 row layout: 512 bytes/node = 128 bf16 (P) + 128 bf16 (Q)
#define PQ_STRIDE 512

__device__ __forceinline__ float silu_f(float x) {
    return x / (1.0f + __expf(-x));
}
__device__ __forceinline__ float sigmoid_f(float x) {
    return 1.0f / (1.0f + __expf(-x));
}

// ---------------------------------------------------------------------------
// Weight prep: transpose all GEMM weights to [N][K] bf16.
// ---------------------------------------------------------------------------
__global__ void k_weights(const float* __restrict__ ew1, const float* __restrict__ ew2,
                          const float* __restrict__ nw1, const float* __restrict__ nw2,
                          const float* __restrict__ cw1, const float* __restrict__ cw2,
                          bf16* __restrict__ projT, bf16* __restrict__ ew2T,
                          bf16* __restrict__ nw1T, bf16* __restrict__ nw2T,
                          bf16* __restrict__ cprojT, bf16* __restrict__ cw2T) {
    int idx = blockIdx.x * 256 + threadIdx.x;
    if (idx < 65536) {                       // projT: 2 layers x [256][128]
        int l = idx >> 15, rem = idx & 32767;
        int n = rem >> 7, k = rem & 127;
        const float* W = ew1 + l * 258 * 128;
        projT[idx] = (bf16)((n < 128) ? W[k * 128 + n] : W[(128 + k) * 128 + (n - 128)]);
    } else if (idx < 98304) {                // ew2T: 2 x [128][128]
        int r = idx - 65536;
        int l = r >> 14, rem = r & 16383;
        int n = rem >> 7, k = rem & 127;
        ew2T[r] = (bf16)(ew2[l * 16384 + k * 128 + n]);
    } else if (idx < 163840) {               // nw1T: 2 x [128][256]
        int r = idx - 98304;
        int l = r >> 15, rem = r & 32767;
        int n = rem >> 8, k = rem & 255;
        nw1T[r] = (bf16)(nw1[l * 32768 + k * 128 + n]);
    } else if (idx < 196608) {               // nw2T: 2 x [128][128]
        int r = idx - 163840;
        int l = r >> 14, rem = r & 16383;
        int n = rem >> 7, k = rem & 127;
        nw2T[r] = (bf16)(nw2[l * 16384 + k * 128 + n]);
    } else if (idx < 229376) {               // cprojT: [256][128]
        int r = idx - 196608;
        int n = r >> 7, k = r & 127;
        cprojT[r] = (bf16)((n < 128) ? cw1[k * 128 + n] : cw1[(128 + k) * 128 + (n - 128)]);
    } else if (idx < 245760) {               // cw2T: [128][128]
        int r = idx - 229376;
        int n = r >> 7, k = r & 127;
        cw2T[r] = (bf16)(cw2[k * 128 + n]);
    }
}

// ---------------------------------------------------------------------------
// Counting sort of edges by destination row (ei[0][e]).
// ---------------------------------------------------------------------------
__global__ void k_hist(const int* __restrict__ ei, int* __restrict__ cnt) {
    int e = blockIdx.x * 256 + threadIdx.x;
    if (e < E_N) atomicAdd(&cnt[ei[e]], 1);
}

__global__ __launch_bounds__(1024) void k_scan(const int* __restrict__ cnt,
                                               int* __restrict__ off) {
    __shared__ int wsum[16];
    __shared__ int wscan[16];
    __shared__ int carry_s;
    int tid = threadIdx.x;
    int lane = tid & 63, wid = tid >> 6;
    if (tid == 0) carry_s = 0;
    __syncthreads();
    for (int base = 0; base < V_N; base += 1024) {
        int carry = carry_s;
        int i = base + tid;
        int v = (i < V_N) ? cnt[i] : 0;
        int val = v;
#pragma unroll
        for (int d = 1; d < 64; d <<= 1) {
            int t = __shfl_up(val, d, 64);
            if (lane >= d) val += t;
        }
        if (lane == 63) wsum[wid] = val;
        __syncthreads();
        if (tid == 0) {
            int s = 0;
#pragma unroll
            for (int k = 0; k < 16; k++) { s += wsum[k]; wscan[k] = s; }
        }
        __syncthreads();
        int wbase = wid ? wscan[wid - 1] : 0;
        if (i < V_N) off[i] = carry + wbase + val - v;
        __syncthreads();
        if (tid == 0) carry_s = carry + wscan[15];
        __syncthreads();
    }
}

__global__ void k_scatter(const int* __restrict__ ei, int* __restrict__ off,
                          int* __restrict__ srow, int* __restrict__ scol,
                          int* __restrict__ perm) {
    int e = blockIdx.x * 256 + threadIdx.x;
    if (e >= E_N) return;
    int r = ei[e], c = ei[E_N + e];
    int p = atomicAdd(&off[r], 1);
    srow[p] = r;
    scol[p] = c;
    perm[p] = e;
}

__global__ void k_edgeprep2(const int* __restrict__ perm, const int* __restrict__ srow,
                            const int* __restrict__ scol, const float* __restrict__ x,
                            const float* __restrict__ eattr,
                            float* __restrict__ cd, float* __restrict__ ea2) {
    int p = blockIdx.x * 256 + threadIdx.x;
    if (p >= E_N) return;
    int e = perm[p];
    int r = srow[p], c = scol[p];
    float dx = x[r * 3 + 0] - x[c * 3 + 0];
    float dy = x[r * 3 + 1] - x[c * 3 + 1];
    float dz = x[r * 3 + 2] - x[c * 3 + 2];
    float rad = dx * dx + dy * dy + dz * dz;
    float inv = 1.0f / (sqrtf(rad + 1e-8f) + 1.0f);
    cd[p * 3 + 0] = dx * inv;
    cd[p * 3 + 1] = dy * inv;
    cd[p * 3 + 2] = dz * inv;
    ea2[p * 2 + 0] = rad;
    ea2[p * 2 + 1] = eattr[e];
}

// ---------------------------------------------------------------------------
// Generic node-level GEMM. opq=1 writes the all-bf16 PQ layout (512B rows).
// ---------------------------------------------------------------------------
__global__ __launch_bounds__(256) void k_node_gemm(
    const float* __restrict__ A1, const float* __restrict__ A2,
    const bf16* __restrict__ BT, const float* __restrict__ bias,
    const float* __restrict__ resid, float* __restrict__ C,
    int M, int K, int Ntot, int act, int opq) {
    __shared__ __align__(16) bf16 Asl[64][136];
    __shared__ __align__(16) bf16 Bsl[128][136];
    int tid = threadIdx.x;
    int m0 = blockIdx.x * 64;
    int n0 = blockIdx.y * 128;
    int lane = tid & 63, w = tid >> 6;
    int q = lane >> 4, l15 = lane & 15;

    f32x4 acc[8];
#pragma unroll
    for (int i = 0; i < 8; i++) acc[i] = (f32x4){0.f, 0.f, 0.f, 0.f};

    for (int kc = 0; kc < K; kc += 128) {
        const float* Asrc = (kc == 0) ? A1 : A2;
#pragma unroll
        for (int p = 0; p < 8; p++) {
            int e4 = (p * 256 + tid) * 4;
            int r = e4 >> 7, k = e4 & 127;
            float4 v = {0.f, 0.f, 0.f, 0.f};
            int row = m0 + r;
            if (row < M) v = *(const float4*)&Asrc[(size_t)row * 128 + k];
            bf16x4 b4 = {(bf16)v.x, (bf16)v.y, (bf16)v.z, (bf16)v.w};
            *(bf16x4*)&Asl[r][k] = b4;
        }
#pragma unroll
        for (int p = 0; p < 8; p++) {
            int e8 = (p * 256 + tid) * 8;
            int n = e8 >> 7, k = e8 & 127;
            bf16x8 v = *(const bf16x8*)&BT[(size_t)(n0 + n) * K + kc + k];
            *(bf16x8*)&Bsl[n][k] = v;
        }
        __syncthreads();
        int ar = w * 16 + l15;
#pragma unroll
        for (int kt = 0; kt < 4; kt++) {
            bf16x8 a = *(const bf16x8*)&Asl[ar][kt * 32 + q * 8];
#pragma unroll
            for (int nt = 0; nt < 8; nt++) {
                bf16x8 b = *(const bf16x8*)&Bsl[nt * 16 + l15][kt * 32 + q * 8];
                acc[nt] = __builtin_amdgcn_mfma_f32_16x16x32_bf16(a, b, acc[nt], 0, 0, 0);
            }
        }
        __syncthreads();
    }
#pragma unroll
    for (int nt = 0; nt < 8; nt++) {
        int col = n0 + nt * 16 + l15;
        float bv = bias ? bias[col] : 0.0f;
#pragma unroll
        for (int reg = 0; reg < 4; reg++) {
            int row = m0 + w * 16 + q * 4 + reg;
            if (row < M) {
                float v = acc[nt][reg] + bv;
                if (act) v = silu_f(v);
                if (resid) v += resid[(size_t)row * 128 + (col & 127)];
                if (opq) {
                    *(bf16*)((char*)C + (size_t)row * PQ_STRIDE + col * 2) = (bf16)v;
                } else {
                    C[(size_t)row * Ntot + col] = v;
                }
            }
        }
    }
}

// ---------------------------------------------------------------------------
// Fused node MLP: h = h + silu([h|agg] @ nw1 + nb1) @ nw2 + nb2
// ---------------------------------------------------------------------------
__global__ __launch_bounds__(256) void k_node_mlp(
    const float* __restrict__ A2,       // agg
    const bf16* __restrict__ B1T,       // nw1T [128][256]
    const float* __restrict__ b1,
    const bf16* __restrict__ B2T,       // nw2T [128][128]
    const float* __restrict__ b2,
    float* __restrict__ H,              // outh, in/out
    int M) {
    __shared__ __align__(16) bf16 Asl[64][136];
    __shared__ __align__(16) bf16 Bsl[128][136];
    int tid = threadIdx.x;
    int m0 = blockIdx.x * 64;
    int lane = tid & 63, w = tid >> 6;
    int q = lane >> 4, l15 = lane & 15;
    int ar = w * 16 + l15;

    f32x4 acc[8];
#pragma unroll
    for (int i = 0; i < 8; i++) acc[i] = (f32x4){0.f, 0.f, 0.f, 0.f};

    for (int kc = 0; kc < 256; kc += 128) {
        const float* Asrc = (kc == 0) ? H : A2;
#pragma unroll
        for (int p = 0; p < 8; p++) {
            int e4 = (p * 256 + tid) * 4;
            int r = e4 >> 7, k = e4 & 127;
            float4 v = {0.f, 0.f, 0.f, 0.f};
            int row = m0 + r;
            if (row < M) v = *(const float4*)&Asrc[(size_t)row * 128 + k];
            bf16x4 b4 = {(bf16)v.x, (bf16)v.y, (bf16)v.z, (bf16)v.w};
            *(bf16x4*)&Asl[r][k] = b4;
        }
#pragma unroll
        for (int p = 0; p < 8; p++) {
            int e8 = (p * 256 + tid) * 8;
            int n = e8 >> 7, k = e8 & 127;
            bf16x8 v = *(const bf16x8*)&B1T[(size_t)n * 256 + kc + k];
            *(bf16x8*)&Bsl[n][k] = v;
        }
        __syncthreads();
#pragma unroll
        for (int kt = 0; kt < 4; kt++) {
            bf16x8 a = *(const bf16x8*)&Asl[ar][kt * 32 + q * 8];
#pragma unroll
            for (int nt = 0; nt < 8; nt++) {
                bf16x8 b = *(const bf16x8*)&Bsl[nt * 16 + l15][kt * 32 + q * 8];
                acc[nt] = __builtin_amdgcn_mfma_f32_16x16x32_bf16(a, b, acc[nt], 0, 0, 0);
            }
        }
        __syncthreads();
    }
#pragma unroll
    for (int nt = 0; nt < 8; nt++) {
        float bv = b1[nt * 16 + l15];
#pragma unroll
        for (int reg = 0; reg < 4; reg++) {
            int r = w * 16 + q * 4 + reg;
            Asl[r][nt * 16 + l15] = (bf16)silu_f(acc[nt][reg] + bv);
        }
    }
#pragma unroll
    for (int p = 0; p < 8; p++) {
        int e8 = (p * 256 + tid) * 8;
        int n = e8 >> 7, k = e8 & 127;
        *(bf16x8*)&Bsl[n][k] = *(const bf16x8*)&B2T[(size_t)n * 128 + k];
    }
    __syncthreads();
    f32x4 acc2[8];
#pragma unroll
    for (int i = 0; i < 8; i++) acc2[i] = (f32x4){0.f, 0.f, 0.f, 0.f};
#pragma unroll
    for (int kt = 0; kt < 4; kt++) {
        bf16x8 a = *(const bf16x8*)&Asl[ar][kt * 32 + q * 8];
#pragma unroll
        for (int nt = 0; nt < 8; nt++) {
            bf16x8 b = *(const bf16x8*)&Bsl[nt * 16 + l15][kt * 32 + q * 8];
            acc2[nt] = __builtin_amdgcn_mfma_f32_16x16x32_bf16(a, b, acc2[nt], 0, 0, 0);
        }
    }
#pragma unroll
    for (int nt = 0; nt < 8; nt++) {
        int col = nt * 16 + l15;
        float bv = b2[col];
#pragma unroll
        for (int reg = 0; reg < 4; reg++) {
            int row = m0 + w * 16 + q * 4 + reg;
            if (row < M) {
                H[(size_t)row * 128 + col] += acc2[nt][reg] + bv;
            }
        }
    }
}

// ---------------------------------------------------------------------------
// Wave-autonomous fused GCL edge kernel: each WAVE owns a 16-edge group
// (one MFMA M-tile). A-fragments built directly in registers in the MFMA
// lane layout; wave-private Fsl slice for the segmented reduce.
// ZERO per-group barriers -> gather stalls decorrelate across waves.
// ---------------------------------------------------------------------------
#define NGROUPS (E_N / 16)

__global__ __launch_bounds__(512, 4) void k_edge_gcl(
    const int* __restrict__ srow, const int* __restrict__ scol,
    const char* __restrict__ PQ,
    const float* __restrict__ ea2, const float* __restrict__ w1c,
    const float* __restrict__ eb1, const bf16* __restrict__ ew2T,
    const float* __restrict__ eb2, const float* __restrict__ aw,
    const float* __restrict__ ab, float* __restrict__ agg) {
    __shared__ __align__(16) bf16 Bsl[128][136];     // persistent weight tile
    __shared__ __align__(16) bf16 Fsl[8][16][136];   // wave-private reduce scratch
    __shared__ __align__(16) float wlds[3][128];     // w0 | w1 | bb broadcast table
    __shared__ int rows_w[8][16];
    int tid = threadIdx.x;
    int lane = tid & 63, w = tid >> 6, q = lane >> 4, l15 = lane & 15;

    // stage B + weight table once (only barrier in the kernel)
#pragma unroll
    for (int p = 0; p < 4; p++) {
        int e8 = (p * 512 + tid) * 8;
        int n = e8 >> 7, k = e8 & 127;
        *(bf16x8*)&Bsl[n][k] = *(const bf16x8*)&ew2T[n * 128 + k];
    }
    if (tid < 128) {
        wlds[0][tid] = w1c[tid];
        wlds[1][tid] = w1c[128 + tid];
        wlds[2][tid] = eb1[tid];
    }
    float b2v[8], awv[8];
#pragma unroll
    for (int nt = 0; nt < 8; nt++) {
        b2v[nt] = eb2[nt * 16 + l15];
        awv[nt] = aw[nt * 16 + l15];
    }
    float ab0 = ab[0];
    __syncthreads();

    int nstreams = gridDim.x * 8;
    for (int g = blockIdx.x * 8 + w; g < NGROUPS; g += nstreams) {
        int e0 = g * 16;
        int ea = e0 + l15;                 // this lane's A-fragment edge
        int row_a = srow[ea], col_a = scol[ea];
        float2 rr = *(const float2*)&ea2[(size_t)ea * 2];
        float ra = rr.x, aa = rr.y;

        // build A-fragments directly in MFMA lane layout
        bf16x8 afrag[4];
#pragma unroll
        for (int kt = 0; kt < 4; kt++) {
            int cb = kt * 32 + q * 8;
            bf16x8 pb = *(const bf16x8*)(PQ + (size_t)row_a * PQ_STRIDE + cb * 2);
            bf16x8 qb = *(const bf16x8*)(PQ + (size_t)col_a * PQ_STRIDE + 256 + cb * 2);
            float4 w0a = *(const float4*)&wlds[0][cb];
            float4 w0b = *(const float4*)&wlds[0][cb + 4];
            float4 w1a = *(const float4*)&wlds[1][cb];
            float4 w1b = *(const float4*)&wlds[1][cb + 4];
            float4 bba = *(const float4*)&wlds[2][cb];
            float4 bbb = *(const float4*)&wlds[2][cb + 4];
            bf16x8 m8;
            float z;
            z = (float)pb[0] + (float)qb[0] + bba.x; z = fmaf(aa, w1a.x, fmaf(ra, w0a.x, z)); m8[0] = (bf16)silu_f(z);
            z = (float)pb[1] + (float)qb[1] + bba.y; z = fmaf(aa, w1a.y, fmaf(ra, w0a.y, z)); m8[1] = (bf16)silu_f(z);
            z = (float)pb[2] + (float)qb[2] + bba.z; z = fmaf(aa, w1a.z, fmaf(ra, w0a.z, z)); m8[2] = (bf16)silu_f(z);
            z = (float)pb[3] + (float)qb[3] + bba.w; z = fmaf(aa, w1a.w, fmaf(ra, w0a.w, z)); m8[3] = (bf16)silu_f(z);
            z = (float)pb[4] + (float)qb[4] + bbb.x; z = fmaf(aa, w1b.x, fmaf(ra, w0b.x, z)); m8[4] = (bf16)silu_f(z);
            z = (float)pb[5] + (float)qb[5] + bbb.y; z = fmaf(aa, w1b.y, fmaf(ra, w0b.y, z)); m8[5] = (bf16)silu_f(z);
            z = (float)pb[6] + (float)qb[6] + bbb.z; z = fmaf(aa, w1b.z, fmaf(ra, w0b.z, z)); m8[6] = (bf16)silu_f(z);
            z = (float)pb[7] + (float)qb[7] + bbb.w; z = fmaf(aa, w1b.w, fmaf(ra, w0b.w, z)); m8[7] = (bf16)silu_f(z);
            afrag[kt] = m8;
        }
        // MFMA: mij-pre = A(16 edges) @ ew2
        f32x4 acc[8];
#pragma unroll
        for (int i = 0; i < 8; i++) acc[i] = (f32x4){0.f, 0.f, 0.f, 0.f};
#pragma unroll
        for (int kt = 0; kt < 4; kt++) {
#pragma unroll
            for (int nt = 0; nt < 8; nt++) {
                bf16x8 b = *(const bf16x8*)&Bsl[nt * 16 + l15][kt * 32 + q * 8];
                acc[nt] = __builtin_amdgcn_mfma_f32_16x16x32_bf16(afrag[kt], b, acc[nt], 0, 0, 0);
            }
        }
        // epilogue: silu + attention dot (rows q*4+reg, cols nt*16+l15)
        float partial[4] = {0.f, 0.f, 0.f, 0.f};
#pragma unroll
        for (int nt = 0; nt < 8; nt++) {
#pragma unroll
            for (int reg = 0; reg < 4; reg++) {
                float mv = silu_f(acc[nt][reg] + b2v[nt]);
                acc[nt][reg] = mv;
                partial[reg] += mv * awv[nt];
            }
        }
        float scale[4];
#pragma unroll
        for (int reg = 0; reg < 4; reg++) {
            float s = partial[reg];
            s += __shfl_xor(s, 1, 16);
            s += __shfl_xor(s, 2, 16);
            s += __shfl_xor(s, 4, 16);
            s += __shfl_xor(s, 8, 16);
            scale[reg] = sigmoid_f(s + ab0) * 0.01f;
        }
        // wave-private Fsl write (no barrier: intra-wave LDS ordering)
#pragma unroll
        for (int reg = 0; reg < 4; reg++) {
            float sc = scale[reg];
#pragma unroll
            for (int nt = 0; nt < 8; nt++) {
                Fsl[w][q * 4 + reg][nt * 16 + l15] = (bf16)(acc[nt][reg] * sc);
            }
        }
        if (lane < 16) rows_w[w][lane] = row_a;   // lanes 0..15: q=0, l15=lane
        // segmented reduce: 2 cols/lane over 16 sorted edges
        int c0 = lane * 2, c1 = c0 + 1;
        float s0 = 0.f, s1 = 0.f;
#pragma unroll
        for (int el = 0; el < 16; ++el) {
            s0 += (float)Fsl[w][el][c0];
            s1 += (float)Fsl[w][el][c1];
            int r = rows_w[w][el];
            int nxt = (el < 15) ? rows_w[w][el + 1] : -1;
            if (r != nxt) {
                atomicAdd(&agg[(size_t)r * 128 + c0], s0);
                atomicAdd(&agg[(size_t)r * 128 + c1], s1);
                s0 = 0.f; s1 = 0.f;
            }
        }
    }
}

// ---------------------------------------------------------------------------
// Wave-autonomous fused coord-update edge kernel (same skeleton)
// ---------------------------------------------------------------------------
__global__ __launch_bounds__(512, 4) void k_edge_coord(
    const int* __restrict__ srow, const int* __restrict__ scol,
    const char* __restrict__ PQ,
    const float* __restrict__ ea2, const float* __restrict__ c1c,
    const float* __restrict__ cb1, const bf16* __restrict__ cw2T,
    const float* __restrict__ cb2, const float* __restrict__ cw3,
    const float* __restrict__ cd, float* __restrict__ xagg) {
    __shared__ __align__(16) bf16 Bsl[128][136];
    __shared__ __align__(16) float wlds[3][128];
    __shared__ int rows_w[8][16];
    __shared__ float s_w[8][16];
    int tid = threadIdx.x;
    int lane = tid & 63, w = tid >> 6, q = lane >> 4, l15 = lane & 15;

#pragma unroll
    for (int p = 0; p < 4; p++) {
        int e8 = (p * 512 + tid) * 8;
        int n = e8 >> 7, k = e8 & 127;
        *(bf16x8*)&Bsl[n][k] = *(const bf16x8*)&cw2T[n * 128 + k];
    }
    if (tid < 128) {
        wlds[0][tid] = c1c[tid];
        wlds[1][tid] = c1c[128 + tid];
        wlds[2][tid] = cb1[tid];
    }
    float b2v[8], w3v[8];
#pragma unroll
    for (int nt = 0; nt < 8; nt++) {
        b2v[nt] = cb2[nt * 16 + l15];
        w3v[nt] = cw3[nt * 16 + l15];
    }
    __syncthreads();

    int nstreams = gridDim.x * 8;
    for (int g = blockIdx.x * 8 + w; g < NGROUPS; g += nstreams) {
        int e0 = g * 16;
        int ea = e0 + l15;
        int row_a = srow[ea], col_a = scol[ea];
        float2 rr = *(const float2*)&ea2[(size_t)ea * 2];
        float ra = rr.x, aa = rr.y;

        bf16x8 afrag[4];
#pragma unroll
        for (int kt = 0; kt < 4; kt++) {
            int cb = kt * 32 + q * 8;
            bf16x8 pb = *(const bf16x8*)(PQ + (size_t)row_a * PQ_STRIDE + cb * 2);
            bf16x8 qb = *(const bf16x8*)(PQ + (size_t)col_a * PQ_STRIDE + 256 + cb * 2);
            float4 w0a = *(const float4*)&wlds[0][cb];
            float4 w0b = *(const float4*)&wlds[0][cb + 4];
            float4 w1a = *(const float4*)&wlds[1][cb];
            float4 w1b = *(const float4*)&wlds[1][cb + 4];
            float4 bba = *(const float4*)&wlds[2][cb];
            float4 bbb = *(const float4*)&wlds[2][cb + 4];
            bf16x8 m8;
            float z;
            z = (float)pb[0] + (float)qb[0] + bba.x; z = fmaf(aa, w1a.x, fmaf(ra, w0a.x, z)); m8[0] = (bf16)silu_f(z);
            z = (float)pb[1] + (float)qb[1] + bba.y; z = fmaf(aa, w1a.y, fmaf(ra, w0a.y, z)); m8[1] = (bf16)silu_f(z);
            z = (float)pb[2] + (float)qb[2] + bba.z; z = fmaf(aa, w1a.z, fmaf(ra, w0a.z, z)); m8[2] = (bf16)silu_f(z);
            z = (float)pb[3] + (float)qb[3] + bba.w; z = fmaf(aa, w1a.w, fmaf(ra, w0a.w, z)); m8[3] = (bf16)silu_f(z);
            z = (float)pb[4] + (float)qb[4] + bbb.x; z = fmaf(aa, w1b.x, fmaf(ra, w0b.x, z)); m8[4] = (bf16)silu_f(z);
            z = (float)pb[5] + (float)qb[5] + bbb.y; z = fmaf(aa, w1b.y, fmaf(ra, w0b.y, z)); m8[5] = (bf16)silu_f(z);
            z = (float)pb[6] + (float)qb[6] + bbb.z; z = fmaf(aa, w1b.z, fmaf(ra, w0b.z, z)); m8[6] = (bf16)silu_f(z);
            z = (float)pb[7] + (float)qb[7] + bbb.w; z = fmaf(aa, w1b.w, fmaf(ra, w0b.w, z)); m8[7] = (bf16)silu_f(z);
            afrag[kt] = m8;
        }
        f32x4 acc[8];
#pragma unroll
        for (int i = 0; i < 8; i++) acc[i] = (f32x4){0.f, 0.f, 0.f, 0.f};
#pragma unroll
        for (int kt = 0; kt < 4; kt++) {
#pragma unroll
            for (int nt = 0; nt < 8; nt++) {
                bf16x8 b = *(const bf16x8*)&Bsl[nt * 16 + l15][kt * 32 + q * 8];
                acc[nt] = __builtin_amdgcn_mfma_f32_16x16x32_bf16(afrag[kt], b, acc[nt], 0, 0, 0);
            }
        }
        float partial[4] = {0.f, 0.f, 0.f, 0.f};
#pragma unroll
        for (int nt = 0; nt < 8; nt++) {
#pragma unroll
            for (int reg = 0; reg < 4; reg++) {
                float tv = silu_f(acc[nt][reg] + b2v[nt]);
                partial[reg] += tv * w3v[nt];
            }
        }
#pragma unroll
        for (int reg = 0; reg < 4; reg++) {
            float s = partial[reg];
            s += __shfl_xor(s, 1, 16);
            s += __shfl_xor(s, 2, 16);
            s += __shfl_xor(s, 4, 16);
            s += __shfl_xor(s, 8, 16);
            if (l15 == 0) s_w[w][q * 4 + reg] = s * 0.01f;
        }
        if (lane < 16) rows_w[w][lane] = row_a;
        // segmented reduce of trans = cd*s (lanes 0..2, one dim each)
        if (lane < 3) {
            int d = lane;
            float sum = 0.f;
#pragma unroll
            for (int el = 0; el < 16; ++el) {
                sum += cd[(size_t)(e0 + el) * 3 + d] * s_w[w][el];
                int r = rows_w[w][el];
                int nxt = (el < 15) ? rows_w[w][el + 1] : -1;
                if (r != nxt) {
                    atomicAdd(&xagg[(size_t)r * 3 + d], sum);
                    sum = 0.f;
                }
            }
        }
    }
}

__global__ void k_finalx(const float* __restrict__ x, const float* __restrict__ xagg,
                         float* __restrict__ outx) {
    int i = blockIdx.x * 256 + threadIdx.x;
    if (i < V_N * 3) outx[i] = x[i] + xagg[i];
}

// ---------------------------------------------------------------------------
extern "C" void kernel_launch(void* const* d_in, const int* in_sizes, int n_in,
                              void* d_out, int out_size, void* d_ws, size_t ws_size,
                              hipStream_t stream) {
    const float* h = (const float*)d_in[0];
    const float* x = (const float*)d_in[1];
    const int* ei = (const int*)d_in[2];
    const float* eattr = (const float*)d_in[3];
    const float* ew1 = (const float*)d_in[4];
    const float* eb1 = (const float*)d_in[5];
    const float* ew2 = (const float*)d_in[6];
    const float* eb2 = (const float*)d_in[7];
    const float* aw = (const float*)d_in[8];
    const float* ab = (const float*)d_in[9];
    const float* nw1 = (const float*)d_in[10];
    const float* nb1 = (const float*)d_in[11];
    const float* nw2 = (const float*)d_in[12];
    const float* nb2 = (const float*)d_in[13];
    const float* cw1 = (const float*)d_in[14];
    const float* cb1 = (const float*)d_in[15];
    const float* cw2 = (const float*)d_in[16];
    const float* cb2 = (const float*)d_in[17];
    const float* cw3 = (const float*)d_in[18];

    char* ws = (char*)d_ws;
    size_t off_b = 0;
    auto alloc = [&](size_t b) {
        size_t o = off_b;
        off_b += (b + 255) & ~(size_t)255;
        return o;
    };
    float* cd = (float*)(ws + alloc((size_t)E_N * 3 * 4));
    float* ea2 = (float*)(ws + alloc((size_t)E_N * 2 * 4));
    char* PQ = (char*)(ws + alloc((size_t)V_N * PQ_STRIDE));
    float* agg = (float*)(ws + alloc((size_t)V_N * 128 * 4));
    float* xagg = (float*)(ws + alloc((size_t)V_N * 3 * 4));
    bf16* projT = (bf16*)(ws + alloc(2 * 256 * 128 * 2));
    bf16* ew2T = (bf16*)(ws + alloc(2 * 128 * 128 * 2));
    bf16* nw1T = (bf16*)(ws + alloc(2 * 128 * 256 * 2));
    bf16* nw2T = (bf16*)(ws + alloc(2 * 128 * 128 * 2));
    bf16* cprojT = (bf16*)(ws + alloc(256 * 128 * 2));
    bf16* cw2T = (bf16*)(ws + alloc(128 * 128 * 2));
    int* cnt = (int*)(ws + alloc((size_t)V_N * 4));
    int* offv = (int*)(ws + alloc((size_t)V_N * 4));
    int* srow = (int*)(ws + alloc((size_t)E_N * 4));
    int* scol = (int*)(ws + alloc((size_t)E_N * 4));
    int* perm = (int*)(ws + alloc((size_t)E_N * 4));

    float* outh = (float*)d_out;
    float* outx = outh + (size_t)V_N * 128;

    hipMemcpyAsync(outh, h, (size_t)V_N * 128 * 4, hipMemcpyDeviceToDevice, stream);
    k_weights<<<960, 256, 0, stream>>>(ew1, ew2, nw1, nw2, cw1, cw2,
                                       projT, ew2T, nw1T, nw2T, cprojT, cw2T);
    // counting sort of edges by row
    hipMemsetAsync(cnt, 0, (size_t)V_N * 4, stream);
    k_hist<<<(E_N + 255) / 256, 256, 0, stream>>>(ei, cnt);
    k_scan<<<1, 1024, 0, stream>>>(cnt, offv);
    k_scatter<<<(E_N + 255) / 256, 256, 0, stream>>>(ei, offv, srow, scol, perm);
    k_edgeprep2<<<(E_N + 255) / 256, 256, 0, stream>>>(perm, srow, scol, x, eattr, cd, ea2);
    hipMemsetAsync(xagg, 0, (size_t)V_N * 3 * 4, stream);

    int mblocks = (V_N + 63) / 64;
    for (int l = 0; l < 2; l++) {
        dim3 gproj(mblocks, 2);
        k_node_gemm<<<gproj, 256, 0, stream>>>(outh, nullptr, projT + (size_t)l * 256 * 128,
                                               nullptr, nullptr, (float*)PQ, V_N, 128, 256, 0, 1);
        hipMemsetAsync(agg, 0, (size_t)V_N * 128 * 4, stream);
        k_edge_gcl<<<512, 512, 0, stream>>>(
            srow, scol, PQ, ea2, ew1 + (size_t)l * 258 * 128 + 256 * 128, eb1 + l * 128,
            ew2T + (size_t)l * 128 * 128, eb2 + l * 128, aw + l * 128, ab + l, agg);
        k_node_mlp<<<mblocks, 256, 0, stream>>>(agg, nw1T + (size_t)l * 128 * 256,
                                                nb1 + l * 128, nw2T + (size_t)l * 128 * 128,
                                                nb2 + l * 128, outh, V_N);
    }
    dim3 gproj(mblocks, 2);
    k_node_gemm<<<gproj, 256, 0, stream>>>(outh, nullptr, cprojT, nullptr, nullptr,
                                           (float*)PQ, V_N, 128, 256, 0, 1);
    k_edge_coord<<<512, 512, 0, stream>>>(srow, scol, PQ, ea2, cw1 + 256 * 128, cb1,
                                          cw2T, cb2, cw3, cd, xagg);
    k_finalx<<<(V_N * 3 + 255) / 256, 256, 0, stream>>>(x, xagg, outx);
}

// Round 10
// 918.958 us; speedup vs baseline: 1.9219x; 1.9219x over previous
//
#include <hip/hip_runtime.h>

#define V_N 50000
#define E_N 800000
#define H_N 128

typedef __bf16 bf16;
typedef bf16 bf16x4 __attribute__((ext_vector_type(4)));
typedef bf16 bf16x8 __attribute__((ext_vector_type(8)));
typedef float f32x4 __attribute__((ext_vector_type(4)));

// PQ all-bf16 row layout: 512 bytes/node = 128 bf16 (P, bias-folded) + 128 bf16 (Q)
#define PQ_STRIDE 512

__device__ __forceinline__ float silu_f(float x) {
    return x / (1.0f + __expf(-x));
}
__device__ __forceinline__ float sigmoid_f(float x) {
    return 1.0f / (1.0f + __expf(-x));
}

// ---------------------------------------------------------------------------
// Weight prep: transpose all GEMM weights to [N][K] bf16 + build PQ bias
// tables (eb1/cb1 folded into the P half of the projection output).
// ---------------------------------------------------------------------------
__global__ void k_weights(const float* __restrict__ ew1, const float* __restrict__ ew2,
                          const float* __restrict__ nw1, const float* __restrict__ nw2,
                          const float* __restrict__ cw1, const float* __restrict__ cw2,
                          const float* __restrict__ eb1, const float* __restrict__ cb1,
                          bf16* __restrict__ projT, bf16* __restrict__ ew2T,
                          bf16* __restrict__ nw1T, bf16* __restrict__ nw2T,
                          bf16* __restrict__ cprojT, bf16* __restrict__ cw2T,
                          float* __restrict__ biasPQ, float* __restrict__ biasCPQ) {
    int idx = blockIdx.x * 256 + threadIdx.x;
    if (idx < 65536) {                       // projT: 2 layers x [256][128]
        int l = idx >> 15, rem = idx & 32767;
        int n = rem >> 7, k = rem & 127;
        const float* W = ew1 + l * 258 * 128;
        projT[idx] = (bf16)((n < 128) ? W[k * 128 + n] : W[(128 + k) * 128 + (n - 128)]);
    } else if (idx < 98304) {                // ew2T: 2 x [128][128]
        int r = idx - 65536;
        int l = r >> 14, rem = r & 16383;
        int n = rem >> 7, k = rem & 127;
        ew2T[r] = (bf16)(ew2[l * 16384 + k * 128 + n]);
    } else if (idx < 163840) {               // nw1T: 2 x [128][256]
        int r = idx - 98304;
        int l = r >> 15, rem = r & 32767;
        int n = rem >> 8, k = rem & 255;
        nw1T[r] = (bf16)(nw1[l * 32768 + k * 128 + n]);
    } else if (idx < 196608) {               // nw2T: 2 x [128][128]
        int r = idx - 163840;
        int l = r >> 14, rem = r & 16383;
        int n = rem >> 7, k = rem & 127;
        nw2T[r] = (bf16)(nw2[l * 16384 + k * 128 + n]);
    } else if (idx < 229376) {               // cprojT: [256][128]
        int r = idx - 196608;
        int n = r >> 7, k = r & 127;
        cprojT[r] = (bf16)((n < 128) ? cw1[k * 128 + n] : cw1[(128 + k) * 128 + (n - 128)]);
    } else if (idx < 245760) {               // cw2T: [128][128]
        int r = idx - 229376;
        int n = r >> 7, k = r & 127;
        cw2T[r] = (bf16)(cw2[k * 128 + n]);
    } else if (idx < 246272) {               // biasPQ: 2 layers x [256]
        int r = idx - 245760;
        int l = r >> 8, c = r & 255;
        biasPQ[r] = (c < 128) ? eb1[l * 128 + c] : 0.0f;
    } else if (idx < 246528) {               // biasCPQ: [256]
        int c = idx - 246272;
        biasCPQ[c] = (c < 128) ? cb1[c] : 0.0f;
    }
}

// ---------------------------------------------------------------------------
// Counting sort of edges by destination row (ei[0][e]).
// ---------------------------------------------------------------------------
__global__ void k_hist(const int* __restrict__ ei, int* __restrict__ cnt) {
    int e = blockIdx.x * 256 + threadIdx.x;
    if (e < E_N) atomicAdd(&cnt[ei[e]], 1);
}

__global__ __launch_bounds__(1024) void k_scan(const int* __restrict__ cnt,
                                               int* __restrict__ off) {
    __shared__ int wsum[16];
    __shared__ int wscan[16];
    __shared__ int carry_s;
    int tid = threadIdx.x;
    int lane = tid & 63, wid = tid >> 6;
    if (tid == 0) carry_s = 0;
    __syncthreads();
    for (int base = 0; base < V_N; base += 1024) {
        int carry = carry_s;
        int i = base + tid;
        int v = (i < V_N) ? cnt[i] : 0;
        int val = v;
#pragma unroll
        for (int d = 1; d < 64; d <<= 1) {
            int t = __shfl_up(val, d, 64);
            if (lane >= d) val += t;
        }
        if (lane == 63) wsum[wid] = val;
        __syncthreads();
        if (tid == 0) {
            int s = 0;
#pragma unroll
            for (int k = 0; k < 16; k++) { s += wsum[k]; wscan[k] = s; }
        }
        __syncthreads();
        int wbase = wid ? wscan[wid - 1] : 0;
        if (i < V_N) off[i] = carry + wbase + val - v;
        __syncthreads();
        if (tid == 0) carry_s = carry + wscan[15];
        __syncthreads();
    }
}

__global__ void k_scatter(const int* __restrict__ ei, int* __restrict__ off,
                          int* __restrict__ srow, int* __restrict__ scol,
                          int* __restrict__ perm) {
    int e = blockIdx.x * 256 + threadIdx.x;
    if (e >= E_N) return;
    int r = ei[e], c = ei[E_N + e];
    int p = atomicAdd(&off[r], 1);
    srow[p] = r;
    scol[p] = c;
    perm[p] = e;
}

__global__ void k_edgeprep2(const int* __restrict__ perm, const int* __restrict__ srow,
                            const int* __restrict__ scol, const float* __restrict__ x,
                            const float* __restrict__ eattr,
                            float* __restrict__ cd, float* __restrict__ ea2) {
    int p = blockIdx.x * 256 + threadIdx.x;
    if (p >= E_N) return;
    int e = perm[p];
    int r = srow[p], c = scol[p];
    float dx = x[r * 3 + 0] - x[c * 3 + 0];
    float dy = x[r * 3 + 1] - x[c * 3 + 1];
    float dz = x[r * 3 + 2] - x[c * 3 + 2];
    float rad = dx * dx + dy * dy + dz * dz;
    float inv = 1.0f / (sqrtf(rad + 1e-8f) + 1.0f);
    cd[p * 3 + 0] = dx * inv;
    cd[p * 3 + 1] = dy * inv;
    cd[p * 3 + 2] = dz * inv;
    ea2[p * 2 + 0] = rad;
    ea2[p * 2 + 1] = eattr[e];
}

// ---------------------------------------------------------------------------
// Generic node-level GEMM. opq=1 writes the all-bf16 PQ layout (512B rows),
// with bias[col] applied (biasPQ folds eb1 into the P half).
// ---------------------------------------------------------------------------
__global__ __launch_bounds__(256) void k_node_gemm(
    const float* __restrict__ A1, const float* __restrict__ A2,
    const bf16* __restrict__ BT, const float* __restrict__ bias,
    const float* __restrict__ resid, float* __restrict__ C,
    int M, int K, int Ntot, int act, int opq) {
    __shared__ __align__(16) bf16 Asl[64][136];
    __shared__ __align__(16) bf16 Bsl[128][136];
    int tid = threadIdx.x;
    int m0 = blockIdx.x * 64;
    int n0 = blockIdx.y * 128;
    int lane = tid & 63, w = tid >> 6;
    int q = lane >> 4, l15 = lane & 15;

    f32x4 acc[8];
#pragma unroll
    for (int i = 0; i < 8; i++) acc[i] = (f32x4){0.f, 0.f, 0.f, 0.f};

    for (int kc = 0; kc < K; kc += 128) {
        const float* Asrc = (kc == 0) ? A1 : A2;
#pragma unroll
        for (int p = 0; p < 8; p++) {
            int e4 = (p * 256 + tid) * 4;
            int r = e4 >> 7, k = e4 & 127;
            float4 v = {0.f, 0.f, 0.f, 0.f};
            int row = m0 + r;
            if (row < M) v = *(const float4*)&Asrc[(size_t)row * 128 + k];
            bf16x4 b4 = {(bf16)v.x, (bf16)v.y, (bf16)v.z, (bf16)v.w};
            *(bf16x4*)&Asl[r][k] = b4;
        }
#pragma unroll
        for (int p = 0; p < 8; p++) {
            int e8 = (p * 256 + tid) * 8;
            int n = e8 >> 7, k = e8 & 127;
            bf16x8 v = *(const bf16x8*)&BT[(size_t)(n0 + n) * K + kc + k];
            *(bf16x8*)&Bsl[n][k] = v;
        }
        __syncthreads();
        int ar = w * 16 + l15;
#pragma unroll
        for (int kt = 0; kt < 4; kt++) {
            bf16x8 a = *(const bf16x8*)&Asl[ar][kt * 32 + q * 8];
#pragma unroll
            for (int nt = 0; nt < 8; nt++) {
                bf16x8 b = *(const bf16x8*)&Bsl[nt * 16 + l15][kt * 32 + q * 8];
                acc[nt] = __builtin_amdgcn_mfma_f32_16x16x32_bf16(a, b, acc[nt], 0, 0, 0);
            }
        }
        __syncthreads();
    }
#pragma unroll
    for (int nt = 0; nt < 8; nt++) {
        int col = n0 + nt * 16 + l15;
        float bv = bias ? bias[col] : 0.0f;
#pragma unroll
        for (int reg = 0; reg < 4; reg++) {
            int row = m0 + w * 16 + q * 4 + reg;
            if (row < M) {
                float v = acc[nt][reg] + bv;
                if (act) v = silu_f(v);
                if (resid) v += resid[(size_t)row * 128 + (col & 127)];
                if (opq) {
                    *(bf16*)((char*)C + (size_t)row * PQ_STRIDE + col * 2) = (bf16)v;
                } else {
                    C[(size_t)row * Ntot + col] = v;
                }
            }
        }
    }
}

// ---------------------------------------------------------------------------
// Fused node MLP + next projection:
//   h = h + silu([h|agg] @ nw1 + nb1) @ nw2 + nb2
//   PQ = hnew @ PT + pbias   (written bf16, 512B rows)
// ---------------------------------------------------------------------------
__global__ __launch_bounds__(256) void k_node_mlp(
    const float* __restrict__ A2,       // agg
    const bf16* __restrict__ B1T,       // nw1T [128][256]
    const float* __restrict__ b1,
    const bf16* __restrict__ B2T,       // nw2T [128][128]
    const float* __restrict__ b2,
    float* __restrict__ H,              // outh, in/out
    int M,
    const bf16* __restrict__ PT,        // next proj [256][128]
    const float* __restrict__ pbias,    // 256 (eb1 in P half, 0 in Q half)
    char* __restrict__ PQout) {
    __shared__ __align__(16) bf16 Asl[64][136];
    __shared__ __align__(16) bf16 Bsl[128][136];
    int tid = threadIdx.x;
    int m0 = blockIdx.x * 64;
    int lane = tid & 63, w = tid >> 6;
    int q = lane >> 4, l15 = lane & 15;
    int ar = w * 16 + l15;

    f32x4 acc[8];
#pragma unroll
    for (int i = 0; i < 8; i++) acc[i] = (f32x4){0.f, 0.f, 0.f, 0.f};

    for (int kc = 0; kc < 256; kc += 128) {
        const float* Asrc = (kc == 0) ? H : A2;
#pragma unroll
        for (int p = 0; p < 8; p++) {
            int e4 = (p * 256 + tid) * 4;
            int r = e4 >> 7, k = e4 & 127;
            float4 v = {0.f, 0.f, 0.f, 0.f};
            int row = m0 + r;
            if (row < M) v = *(const float4*)&Asrc[(size_t)row * 128 + k];
            bf16x4 b4 = {(bf16)v.x, (bf16)v.y, (bf16)v.z, (bf16)v.w};
            *(bf16x4*)&Asl[r][k] = b4;
        }
#pragma unroll
        for (int p = 0; p < 8; p++) {
            int e8 = (p * 256 + tid) * 8;
            int n = e8 >> 7, k = e8 & 127;
            bf16x8 v = *(const bf16x8*)&B1T[(size_t)n * 256 + kc + k];
            *(bf16x8*)&Bsl[n][k] = v;
        }
        __syncthreads();
#pragma unroll
        for (int kt = 0; kt < 4; kt++) {
            bf16x8 a = *(const bf16x8*)&Asl[ar][kt * 32 + q * 8];
#pragma unroll
            for (int nt = 0; nt < 8; nt++) {
                bf16x8 b = *(const bf16x8*)&Bsl[nt * 16 + l15][kt * 32 + q * 8];
                acc[nt] = __builtin_amdgcn_mfma_f32_16x16x32_bf16(a, b, acc[nt], 0, 0, 0);
            }
        }
        __syncthreads();
    }
#pragma unroll
    for (int nt = 0; nt < 8; nt++) {
        float bv = b1[nt * 16 + l15];
#pragma unroll
        for (int reg = 0; reg < 4; reg++) {
            int r = w * 16 + q * 4 + reg;
            Asl[r][nt * 16 + l15] = (bf16)silu_f(acc[nt][reg] + bv);
        }
    }
#pragma unroll
    for (int p = 0; p < 8; p++) {
        int e8 = (p * 256 + tid) * 8;
        int n = e8 >> 7, k = e8 & 127;
        *(bf16x8*)&Bsl[n][k] = *(const bf16x8*)&B2T[(size_t)n * 128 + k];
    }
    __syncthreads();
    f32x4 acc2[8];
#pragma unroll
    for (int i = 0; i < 8; i++) acc2[i] = (f32x4){0.f, 0.f, 0.f, 0.f};
#pragma unroll
    for (int kt = 0; kt < 4; kt++) {
        bf16x8 a = *(const bf16x8*)&Asl[ar][kt * 32 + q * 8];
#pragma unroll
        for (int nt = 0; nt < 8; nt++) {
            bf16x8 b = *(const bf16x8*)&Bsl[nt * 16 + l15][kt * 32 + q * 8];
            acc2[nt] = __builtin_amdgcn_mfma_f32_16x16x32_bf16(a, b, acc2[nt], 0, 0, 0);
        }
    }
    // residual add -> Hnew (kept in acc2)
#pragma unroll
    for (int nt = 0; nt < 8; nt++) {
        int col = nt * 16 + l15;
        float bv = b2[col];
#pragma unroll
        for (int reg = 0; reg < 4; reg++) {
            int row = m0 + w * 16 + q * 4 + reg;
            if (row < M) {
                float hv = H[(size_t)row * 128 + col] + acc2[nt][reg] + bv;
                H[(size_t)row * 128 + col] = hv;
                acc2[nt][reg] = hv;
            }
        }
    }
    __syncthreads();   // all GEMM2 LDS reads done
    // Hnew -> Asl bf16 A-tile for the fused projection
#pragma unroll
    for (int nt = 0; nt < 8; nt++) {
#pragma unroll
        for (int reg = 0; reg < 4; reg++) {
            int r = w * 16 + q * 4 + reg;
            Asl[r][nt * 16 + l15] = (bf16)acc2[nt][reg];
        }
    }
    // fused projection: PQ = Hnew @ PT + pbias, two 128-col halves
    for (int half = 0; half < 2; half++) {
#pragma unroll
        for (int p = 0; p < 8; p++) {
            int e8 = (p * 256 + tid) * 8;
            int n = e8 >> 7, k = e8 & 127;
            *(bf16x8*)&Bsl[n][k] = *(const bf16x8*)&PT[(size_t)(half * 128 + n) * 128 + k];
        }
        __syncthreads();
        f32x4 accp[8];
#pragma unroll
        for (int i = 0; i < 8; i++) accp[i] = (f32x4){0.f, 0.f, 0.f, 0.f};
#pragma unroll
        for (int kt = 0; kt < 4; kt++) {
            bf16x8 a = *(const bf16x8*)&Asl[ar][kt * 32 + q * 8];
#pragma unroll
            for (int nt = 0; nt < 8; nt++) {
                bf16x8 b = *(const bf16x8*)&Bsl[nt * 16 + l15][kt * 32 + q * 8];
                accp[nt] = __builtin_amdgcn_mfma_f32_16x16x32_bf16(a, b, accp[nt], 0, 0, 0);
            }
        }
#pragma unroll
        for (int nt = 0; nt < 8; nt++) {
            int colg = half * 128 + nt * 16 + l15;
            float bv = pbias[colg];
#pragma unroll
            for (int reg = 0; reg < 4; reg++) {
                int row = m0 + w * 16 + q * 4 + reg;
                if (row < M) {
                    *(bf16*)(PQout + (size_t)row * PQ_STRIDE + colg * 2) =
                        (bf16)(accp[nt][reg] + bv);
                }
            }
        }
        __syncthreads();
    }
}

// ---------------------------------------------------------------------------
// Persistent fused GCL edge kernel: 512 threads, 128 sorted edges/tile.
// (Round-8 structure; eb1 folded into P so no bias add here.)
// ---------------------------------------------------------------------------
#define NTILES (E_N / 128)

__global__ __launch_bounds__(512, 4) void k_edge_gcl(
    const int* __restrict__ srow, const int* __restrict__ scol,
    const char* __restrict__ PQ,
    const float* __restrict__ ea2, const float* __restrict__ w1c,
    const bf16* __restrict__ ew2T,
    const float* __restrict__ eb2, const float* __restrict__ aw,
    const float* __restrict__ ab, float* __restrict__ agg) {
    __shared__ __align__(16) bf16 Asl[128][136];   // A-tile; reused as bf16 Fsl
    __shared__ __align__(16) bf16 Bsl[128][136];   // persistent weight tile
    __shared__ int rows_s[128];
    __shared__ int cols_s[128];
    __shared__ float ra_s[128], aa_s[128];
    int tid = threadIdx.x;
    int lane = tid & 63, w = tid >> 6, q = lane >> 4, l15 = lane & 15;
    int j = (tid & 31) * 4;   // fixed column group per thread
    int eslot = tid >> 5;     // edge sub-slot (0..15)

    // stage B once
#pragma unroll
    for (int p = 0; p < 4; p++) {
        int e8 = (p * 512 + tid) * 8;
        int n = e8 >> 7, k = e8 & 127;
        *(bf16x8*)&Bsl[n][k] = *(const bf16x8*)&ew2T[n * 128 + k];
    }
    float4 w0r = *(const float4*)&w1c[j];
    float4 w1r = *(const float4*)&w1c[128 + j];
    float b2v[8], awv[8];
#pragma unroll
    for (int nt = 0; nt < 8; nt++) {
        b2v[nt] = eb2[nt * 16 + l15];
        awv[nt] = aw[nt * 16 + l15];
    }
    float ab0 = ab[0];

    for (int t = blockIdx.x; t < NTILES; t += gridDim.x) {
        int e0 = t * 128;
        __syncthreads();   // prev tile's seg-reduce done (Asl/rows_s free)
        if (tid < 128) {
            int e = e0 + tid;
            rows_s[tid] = srow[e];
            cols_s[tid] = scol[e];
            float2 rr = *(const float2*)&ea2[(size_t)e * 2];
            ra_s[tid] = rr.x;
            aa_s[tid] = rr.y;
        }
        __syncthreads();
        // stage A: issue all 16 gathers, then compute
        bf16x4 pb[8];
        bf16x4 qb[8];
#pragma unroll
        for (int p = 0; p < 8; p++) {
            int el = p * 16 + eslot;
            int row = rows_s[el], col = cols_s[el];
            pb[p] = *(const bf16x4*)(PQ + (size_t)row * PQ_STRIDE + j * 2);
            qb[p] = *(const bf16x4*)(PQ + (size_t)col * PQ_STRIDE + 256 + j * 2);
        }
#pragma unroll
        for (int p = 0; p < 8; p++) {
            int el = p * 16 + eslot;
            float ra = ra_s[el], aa = aa_s[el];
            float zx = (float)pb[p][0] + (float)qb[p][0];
            float zy = (float)pb[p][1] + (float)qb[p][1];
            float zz = (float)pb[p][2] + (float)qb[p][2];
            float zw = (float)pb[p][3] + (float)qb[p][3];
            zx = fmaf(aa, w1r.x, fmaf(ra, w0r.x, zx));
            zy = fmaf(aa, w1r.y, fmaf(ra, w0r.y, zy));
            zz = fmaf(aa, w1r.z, fmaf(ra, w0r.z, zz));
            zw = fmaf(aa, w1r.w, fmaf(ra, w0r.w, zw));
            bf16x4 b4 = {(bf16)silu_f(zx), (bf16)silu_f(zy),
                         (bf16)silu_f(zz), (bf16)silu_f(zw)};
            *(bf16x4*)&Asl[el][j] = b4;
        }
        __syncthreads();
        f32x4 acc[8];
#pragma unroll
        for (int i = 0; i < 8; i++) acc[i] = (f32x4){0.f, 0.f, 0.f, 0.f};
        int ar = w * 16 + l15;
#pragma unroll
        for (int kt = 0; kt < 4; kt++) {
            bf16x8 a = *(const bf16x8*)&Asl[ar][kt * 32 + q * 8];
#pragma unroll
            for (int nt = 0; nt < 8; nt++) {
                bf16x8 b = *(const bf16x8*)&Bsl[nt * 16 + l15][kt * 32 + q * 8];
                acc[nt] = __builtin_amdgcn_mfma_f32_16x16x32_bf16(a, b, acc[nt], 0, 0, 0);
            }
        }
        // epilogue in regs: silu + attention dot
        float partial[4] = {0.f, 0.f, 0.f, 0.f};
#pragma unroll
        for (int nt = 0; nt < 8; nt++) {
#pragma unroll
            for (int reg = 0; reg < 4; reg++) {
                float mv = silu_f(acc[nt][reg] + b2v[nt]);
                acc[nt][reg] = mv;
                partial[reg] += mv * awv[nt];
            }
        }
        float scale[4];
#pragma unroll
        for (int reg = 0; reg < 4; reg++) {
            float s = partial[reg];
            s += __shfl_xor(s, 1, 16);
            s += __shfl_xor(s, 2, 16);
            s += __shfl_xor(s, 4, 16);
            s += __shfl_xor(s, 8, 16);
            scale[reg] = sigmoid_f(s + ab0) * 0.01f;
        }
        __syncthreads();   // all Asl MFMA reads done -> overlay Fsl (bf16)
#pragma unroll
        for (int reg = 0; reg < 4; reg++) {
            int er = w * 16 + q * 4 + reg;
            float sc = scale[reg];
#pragma unroll
            for (int nt = 0; nt < 8; nt++) {
                Asl[er][nt * 16 + l15] = (bf16)(acc[nt][reg] * sc);
            }
        }
        __syncthreads();
        // segmented reduction over sorted-row runs: quarter of 32 edges each
        int col = tid & 127, quarter = tid >> 7;
        int es = quarter * 32, ee = es + 32;
        float sum = 0.f;
        for (int el = es; el < ee; ++el) {
            sum += (float)Asl[el][col];
            int r = rows_s[el];
            int nxt = (el + 1 < ee) ? rows_s[el + 1] : -1;
            if (r != nxt) {
                atomicAdd(&agg[(size_t)r * 128 + col], sum);
                sum = 0.f;
            }
        }
    }
}

// ---------------------------------------------------------------------------
// Persistent fused coord-update edge kernel (cb1 folded into P)
// ---------------------------------------------------------------------------
__global__ __launch_bounds__(512, 4) void k_edge_coord(
    const int* __restrict__ srow, const int* __restrict__ scol,
    const char* __restrict__ PQ,
    const float* __restrict__ ea2, const float* __restrict__ c1c,
    const bf16* __restrict__ cw2T,
    const float* __restrict__ cb2, const float* __restrict__ cw3,
    const float* __restrict__ cd, float* __restrict__ xagg) {
    __shared__ __align__(16) bf16 Asl[128][136];
    __shared__ __align__(16) bf16 Bsl[128][136];
    __shared__ int rows_s[128];
    __shared__ int cols_s[128];
    __shared__ float ra_s[128], aa_s[128];
    __shared__ float cds[384];
    __shared__ float Ssl[128];
    int tid = threadIdx.x;
    int lane = tid & 63, w = tid >> 6, q = lane >> 4, l15 = lane & 15;
    int j = (tid & 31) * 4;
    int eslot = tid >> 5;

#pragma unroll
    for (int p = 0; p < 4; p++) {
        int e8 = (p * 512 + tid) * 8;
        int n = e8 >> 7, k = e8 & 127;
        *(bf16x8*)&Bsl[n][k] = *(const bf16x8*)&cw2T[n * 128 + k];
    }
    float4 w0r = *(const float4*)&c1c[j];
    float4 w1r = *(const float4*)&c1c[128 + j];
    float b2v[8], w3v[8];
#pragma unroll
    for (int nt = 0; nt < 8; nt++) {
        b2v[nt] = cb2[nt * 16 + l15];
        w3v[nt] = cw3[nt * 16 + l15];
    }

    for (int t = blockIdx.x; t < NTILES; t += gridDim.x) {
        int e0 = t * 128;
        __syncthreads();
        if (tid < 128) {
            int e = e0 + tid;
            rows_s[tid] = srow[e];
            cols_s[tid] = scol[e];
            float2 rr = *(const float2*)&ea2[(size_t)e * 2];
            ra_s[tid] = rr.x;
            aa_s[tid] = rr.y;
        }
        if (tid < 384) cds[tid] = cd[(size_t)e0 * 3 + tid];
        __syncthreads();
        bf16x4 pb[8];
        bf16x4 qb[8];
#pragma unroll
        for (int p = 0; p < 8; p++) {
            int el = p * 16 + eslot;
            int row = rows_s[el], col = cols_s[el];
            pb[p] = *(const bf16x4*)(PQ + (size_t)row * PQ_STRIDE + j * 2);
            qb[p] = *(const bf16x4*)(PQ + (size_t)col * PQ_STRIDE + 256 + j * 2);
        }
#pragma unroll
        for (int p = 0; p < 8; p++) {
            int el = p * 16 + eslot;
            float ra = ra_s[el], aa = aa_s[el];
            float zx = (float)pb[p][0] + (float)qb[p][0];
            float zy = (float)pb[p][1] + (float)qb[p][1];
            float zz = (float)pb[p][2] + (float)qb[p][2];
            float zw = (float)pb[p][3] + (float)qb[p][3];
            zx = fmaf(aa, w1r.x, fmaf(ra, w0r.x, zx));
            zy = fmaf(aa, w1r.y, fmaf(ra, w0r.y, zy));
            zz = fmaf(aa, w1r.z, fmaf(ra, w0r.z, zz));
            zw = fmaf(aa, w1r.w, fmaf(ra, w0r.w, zw));
            bf16x4 b4 = {(bf16)silu_f(zx), (bf16)silu_f(zy),
                         (bf16)silu_f(zz), (bf16)silu_f(zw)};
            *(bf16x4*)&Asl[el][j] = b4;
        }
        __syncthreads();
        f32x4 acc[8];
#pragma unroll
        for (int i = 0; i < 8; i++) acc[i] = (f32x4){0.f, 0.f, 0.f, 0.f};
        int ar = w * 16 + l15;
#pragma unroll
        for (int kt = 0; kt < 4; kt++) {
            bf16x8 a = *(const bf16x8*)&Asl[ar][kt * 32 + q * 8];
#pragma unroll
            for (int nt = 0; nt < 8; nt++) {
                bf16x8 b = *(const bf16x8*)&Bsl[nt * 16 + l15][kt * 32 + q * 8];
                acc[nt] = __builtin_amdgcn_mfma_f32_16x16x32_bf16(a, b, acc[nt], 0, 0, 0);
            }
        }
        float partial[4] = {0.f, 0.f, 0.f, 0.f};
#pragma unroll
        for (int nt = 0; nt < 8; nt++) {
#pragma unroll
            for (int reg = 0; reg < 4; reg++) {
                float tv = silu_f(acc[nt][reg] + b2v[nt]);
                partial[reg] += tv * w3v[nt];
            }
        }
#pragma unroll
        for (int reg = 0; reg < 4; reg++) {
            float s = partial[reg];
            s += __shfl_xor(s, 1, 16);
            s += __shfl_xor(s, 2, 16);
            s += __shfl_xor(s, 4, 16);
            s += __shfl_xor(s, 8, 16);
            if (l15 == 0) Ssl[w * 16 + q * 4 + reg] = s * 0.01f;
        }
        __syncthreads();
        // segmented reduce of trans = cd*s over sorted-row runs (48 thr x 8)
        if (tid < 48) {
            int d = tid % 3, chunk = tid / 3;
            int es = chunk * 8, ee = es + 8;
            float sum = 0.f;
            for (int el = es; el < ee; ++el) {
                sum += cds[el * 3 + d] * Ssl[el];
                int r = rows_s[el];
                int nxt = (el + 1 < ee) ? rows_s[el + 1] : -1;
                if (r != nxt) {
                    atomicAdd(&xagg[(size_t)r * 3 + d], sum);
                    sum = 0.f;
                }
            }
        }
    }
}

__global__ void k_finalx(const float* __restrict__ x, const float* __restrict__ xagg,
                         float* __restrict__ outx) {
    int i = blockIdx.x * 256 + threadIdx.x;
    if (i < V_N * 3) outx[i] = x[i] + xagg[i];
}

// ---------------------------------------------------------------------------
extern "C" void kernel_launch(void* const* d_in, const int* in_sizes, int n_in,
                              void* d_out, int out_size, void* d_ws, size_t ws_size,
                              hipStream_t stream) {
    const float* h = (const float*)d_in[0];
    const float* x = (const float*)d_in[1];
    const int* ei = (const int*)d_in[2];
    const float* eattr = (const float*)d_in[3];
    const float* ew1 = (const float*)d_in[4];
    const float* eb1 = (const float*)d_in[5];
    const float* ew2 = (const float*)d_in[6];
    const float* eb2 = (const float*)d_in[7];
    const float* aw = (const float*)d_in[8];
    const float* ab = (const float*)d_in[9];
    const float* nw1 = (const float*)d_in[10];
    const float* nb1 = (const float*)d_in[11];
    const float* nw2 = (const float*)d_in[12];
    const float* nb2 = (const float*)d_in[13];
    const float* cw1 = (const float*)d_in[14];
    const float* cb1 = (const float*)d_in[15];
    const float* cw2 = (const float*)d_in[16];
    const float* cb2 = (const float*)d_in[17];
    const float* cw3 = (const float*)d_in[18];

    char* ws = (char*)d_ws;
    size_t off_b = 0;
    auto alloc = [&](size_t b) {
        size_t o = off_b;
        off_b += (b + 255) & ~(size_t)255;
        return o;
    };
    float* cd = (float*)(ws + alloc((size_t)E_N * 3 * 4));
    float* ea2 = (float*)(ws + alloc((size_t)E_N * 2 * 4));
    char* PQ = (char*)(ws + alloc((size_t)V_N * PQ_STRIDE));
    float* agg = (float*)(ws + alloc((size_t)V_N * 128 * 4));
    float* xagg = (float*)(ws + alloc((size_t)V_N * 3 * 4));
    bf16* projT = (bf16*)(ws + alloc(2 * 256 * 128 * 2));
    bf16* ew2T = (bf16*)(ws + alloc(2 * 128 * 128 * 2));
    bf16* nw1T = (bf16*)(ws + alloc(2 * 128 * 256 * 2));
    bf16* nw2T = (bf16*)(ws + alloc(2 * 128 * 128 * 2));
    bf16* cprojT = (bf16*)(ws + alloc(256 * 128 * 2));
    bf16* cw2T = (bf16*)(ws + alloc(128 * 128 * 2));
    float* biasPQ = (float*)(ws + alloc(2 * 256 * 4));
    float* biasCPQ = (float*)(ws + alloc(256 * 4));
    int* cnt = (int*)(ws + alloc((size_t)V_N * 4));
    int* offv = (int*)(ws + alloc((size_t)V_N * 4));
    int* srow = (int*)(ws + alloc((size_t)E_N * 4));
    int* scol = (int*)(ws + alloc((size_t)E_N * 4));
    int* perm = (int*)(ws + alloc((size_t)E_N * 4));

    float* outh = (float*)d_out;
    float* outx = outh + (size_t)V_N * 128;

    hipMemcpyAsync(outh, h, (size_t)V_N * 128 * 4, hipMemcpyDeviceToDevice, stream);
    k_weights<<<964, 256, 0, stream>>>(ew1, ew2, nw1, nw2, cw1, cw2, eb1, cb1,
                                       projT, ew2T, nw1T, nw2T, cprojT, cw2T,
                                       biasPQ, biasCPQ);
    // counting sort of edges by row
    hipMemsetAsync(cnt, 0, (size_t)V_N * 4, stream);
    k_hist<<<(E_N + 255) / 256, 256, 0, stream>>>(ei, cnt);
    k_scan<<<1, 1024, 0, stream>>>(cnt, offv);
    k_scatter<<<(E_N + 255) / 256, 256, 0, stream>>>(ei, offv, srow, scol, perm);
    k_edgeprep2<<<(E_N + 255) / 256, 256, 0, stream>>>(perm, srow, scol, x, eattr, cd, ea2);
    hipMemsetAsync(xagg, 0, (size_t)V_N * 3 * 4, stream);

    int mblocks = (V_N + 63) / 64;
    // layer 0: standalone projection (bias-folded)
    dim3 gproj(mblocks, 2);
    k_node_gemm<<<gproj, 256, 0, stream>>>(outh, nullptr, projT, biasPQ, nullptr,
                                           (float*)PQ, V_N, 128, 256, 0, 1);
    hipMemsetAsync(agg, 0, (size_t)V_N * 128 * 4, stream);
    k_edge_gcl<<<512, 512, 0, stream>>>(
        srow, scol, PQ, ea2, ew1 + 256 * 128,
        ew2T, eb2, aw, ab, agg);
    // node MLP 0 + fused projection for layer 1
    k_node_mlp<<<mblocks, 256, 0, stream>>>(agg, nw1T, nb1, nw2T, nb2, outh, V_N,
                                            projT + 256 * 128, biasPQ + 256, PQ);
    hipMemsetAsync(agg, 0, (size_t)V_N * 128 * 4, stream);
    k_edge_gcl<<<512, 512, 0, stream>>>(
        srow, scol, PQ, ea2, ew1 + (size_t)1 * 258 * 128 + 256 * 128,
        ew2T + 128 * 128, eb2 + 128, aw + 128, ab + 1, agg);
    // node MLP 1 + fused coord projection
    k_node_mlp<<<mblocks, 256, 0, stream>>>(agg, nw1T + 128 * 256, nb1 + 128,
                                            nw2T + 128 * 128, nb2 + 128, outh, V_N,
                                            cprojT, biasCPQ, PQ);
    k_edge_coord<<<512, 512, 0, stream>>>(srow, scol, PQ, ea2, cw1 + 256 * 128,
                                          cw2T, cb2, cw3, cd, xagg);
    k_finalx<<<(V_N * 3 + 255) / 256, 256, 0, stream>>>(x, xagg, outx);
}

// Round 11
// 771.704 us; speedup vs baseline: 2.2886x; 1.1908x over previous
//
#include <hip/hip_runtime.h>

#define V_N 50000
#define E_N 800000
#define H_N 128

typedef __bf16 bf16;
typedef bf16 bf16x4 __attribute__((ext_vector_type(4)));
typedef bf16 bf16x8 __attribute__((ext_vector_type(8)));
typedef float f32x4 __attribute__((ext_vector_type(4)));

// PQ all-bf16 row layout: 512 bytes/node = 128 bf16 (P, bias-folded) + 128 bf16 (Q)
#define PQ_STRIDE 512

// Fast silu/sigmoid: v_rcp_f32 instead of the IEEE divide sequence.
// ~1-ulp rcp error is invisible at bf16 rounding / 0.03 tolerance.
__device__ __forceinline__ float silu_f(float x) {
    return x * __builtin_amdgcn_rcpf(1.0f + __expf(-x));
}
__device__ __forceinline__ float sigmoid_f(float x) {
    return __builtin_amdgcn_rcpf(1.0f + __expf(-x));
}

// ---------------------------------------------------------------------------
// Weight prep: transpose all GEMM weights to [N][K] bf16 + build PQ bias
// tables (eb1/cb1 folded into the P half of the projection output).
// ---------------------------------------------------------------------------
__global__ void k_weights(const float* __restrict__ ew1, const float* __restrict__ ew2,
                          const float* __restrict__ nw1, const float* __restrict__ nw2,
                          const float* __restrict__ cw1, const float* __restrict__ cw2,
                          const float* __restrict__ eb1, const float* __restrict__ cb1,
                          bf16* __restrict__ projT, bf16* __restrict__ ew2T,
                          bf16* __restrict__ nw1T, bf16* __restrict__ nw2T,
                          bf16* __restrict__ cprojT, bf16* __restrict__ cw2T,
                          float* __restrict__ biasPQ, float* __restrict__ biasCPQ) {
    int idx = blockIdx.x * 256 + threadIdx.x;
    if (idx < 65536) {                       // projT: 2 layers x [256][128]
        int l = idx >> 15, rem = idx & 32767;
        int n = rem >> 7, k = rem & 127;
        const float* W = ew1 + l * 258 * 128;
        projT[idx] = (bf16)((n < 128) ? W[k * 128 + n] : W[(128 + k) * 128 + (n - 128)]);
    } else if (idx < 98304) {                // ew2T: 2 x [128][128]
        int r = idx - 65536;
        int l = r >> 14, rem = r & 16383;
        int n = rem >> 7, k = rem & 127;
        ew2T[r] = (bf16)(ew2[l * 16384 + k * 128 + n]);
    } else if (idx < 163840) {               // nw1T: 2 x [128][256]
        int r = idx - 98304;
        int l = r >> 15, rem = r & 32767;
        int n = rem >> 8, k = rem & 255;
        nw1T[r] = (bf16)(nw1[l * 32768 + k * 128 + n]);
    } else if (idx < 196608) {               // nw2T: 2 x [128][128]
        int r = idx - 163840;
        int l = r >> 14, rem = r & 16383;
        int n = rem >> 7, k = rem & 127;
        nw2T[r] = (bf16)(nw2[l * 16384 + k * 128 + n]);
    } else if (idx < 229376) {               // cprojT: [256][128]
        int r = idx - 196608;
        int n = r >> 7, k = r & 127;
        cprojT[r] = (bf16)((n < 128) ? cw1[k * 128 + n] : cw1[(128 + k) * 128 + (n - 128)]);
    } else if (idx < 245760) {               // cw2T: [128][128]
        int r = idx - 229376;
        int n = r >> 7, k = r & 127;
        cw2T[r] = (bf16)(cw2[k * 128 + n]);
    } else if (idx < 246272) {               // biasPQ: 2 layers x [256]
        int r = idx - 245760;
        int l = r >> 8, c = r & 255;
        biasPQ[r] = (c < 128) ? eb1[l * 128 + c] : 0.0f;
    } else if (idx < 246528) {               // biasCPQ: [256]
        int c = idx - 246272;
        biasCPQ[c] = (c < 128) ? cb1[c] : 0.0f;
    }
}

// ---------------------------------------------------------------------------
// Counting sort of edges by destination row (ei[0][e]).
// ---------------------------------------------------------------------------
__global__ void k_hist(const int* __restrict__ ei, int* __restrict__ cnt) {
    int e = blockIdx.x * 256 + threadIdx.x;
    if (e < E_N) atomicAdd(&cnt[ei[e]], 1);
}

__global__ __launch_bounds__(1024) void k_scan(const int* __restrict__ cnt,
                                               int* __restrict__ off) {
    __shared__ int wsum[16];
    __shared__ int wscan[16];
    __shared__ int carry_s;
    int tid = threadIdx.x;
    int lane = tid & 63, wid = tid >> 6;
    if (tid == 0) carry_s = 0;
    __syncthreads();
    for (int base = 0; base < V_N; base += 1024) {
        int carry = carry_s;
        int i = base + tid;
        int v = (i < V_N) ? cnt[i] : 0;
        int val = v;
#pragma unroll
        for (int d = 1; d < 64; d <<= 1) {
            int t = __shfl_up(val, d, 64);
            if (lane >= d) val += t;
        }
        if (lane == 63) wsum[wid] = val;
        __syncthreads();
        if (tid == 0) {
            int s = 0;
#pragma unroll
            for (int k = 0; k < 16; k++) { s += wsum[k]; wscan[k] = s; }
        }
        __syncthreads();
        int wbase = wid ? wscan[wid - 1] : 0;
        if (i < V_N) off[i] = carry + wbase + val - v;
        __syncthreads();
        if (tid == 0) carry_s = carry + wscan[15];
        __syncthreads();
    }
}

__global__ void k_scatter(const int* __restrict__ ei, int* __restrict__ off,
                          int* __restrict__ srow, int* __restrict__ scol,
                          int* __restrict__ perm) {
    int e = blockIdx.x * 256 + threadIdx.x;
    if (e >= E_N) return;
    int r = ei[e], c = ei[E_N + e];
    int p = atomicAdd(&off[r], 1);
    srow[p] = r;
    scol[p] = c;
    perm[p] = e;
}

__global__ void k_edgeprep2(const int* __restrict__ perm, const int* __restrict__ srow,
                            const int* __restrict__ scol, const float* __restrict__ x,
                            const float* __restrict__ eattr,
                            float* __restrict__ cd, float* __restrict__ ea2) {
    int p = blockIdx.x * 256 + threadIdx.x;
    if (p >= E_N) return;
    int e = perm[p];
    int r = srow[p], c = scol[p];
    float dx = x[r * 3 + 0] - x[c * 3 + 0];
    float dy = x[r * 3 + 1] - x[c * 3 + 1];
    float dz = x[r * 3 + 2] - x[c * 3 + 2];
    float rad = dx * dx + dy * dy + dz * dz;
    float inv = 1.0f / (sqrtf(rad + 1e-8f) + 1.0f);
    cd[p * 3 + 0] = dx * inv;
    cd[p * 3 + 1] = dy * inv;
    cd[p * 3 + 2] = dz * inv;
    ea2[p * 2 + 0] = rad;
    ea2[p * 2 + 1] = eattr[e];
}

// ---------------------------------------------------------------------------
// Generic node-level GEMM. opq=1 writes the all-bf16 PQ layout (512B rows),
// with bias[col] applied (biasPQ folds eb1 into the P half).
// ---------------------------------------------------------------------------
__global__ __launch_bounds__(256) void k_node_gemm(
    const float* __restrict__ A1, const float* __restrict__ A2,
    const bf16* __restrict__ BT, const float* __restrict__ bias,
    const float* __restrict__ resid, float* __restrict__ C,
    int M, int K, int Ntot, int act, int opq) {
    __shared__ __align__(16) bf16 Asl[64][136];
    __shared__ __align__(16) bf16 Bsl[128][136];
    int tid = threadIdx.x;
    int m0 = blockIdx.x * 64;
    int n0 = blockIdx.y * 128;
    int lane = tid & 63, w = tid >> 6;
    int q = lane >> 4, l15 = lane & 15;

    f32x4 acc[8];
#pragma unroll
    for (int i = 0; i < 8; i++) acc[i] = (f32x4){0.f, 0.f, 0.f, 0.f};

    for (int kc = 0; kc < K; kc += 128) {
        const float* Asrc = (kc == 0) ? A1 : A2;
#pragma unroll
        for (int p = 0; p < 8; p++) {
            int e4 = (p * 256 + tid) * 4;
            int r = e4 >> 7, k = e4 & 127;
            float4 v = {0.f, 0.f, 0.f, 0.f};
            int row = m0 + r;
            if (row < M) v = *(const float4*)&Asrc[(size_t)row * 128 + k];
            bf16x4 b4 = {(bf16)v.x, (bf16)v.y, (bf16)v.z, (bf16)v.w};
            *(bf16x4*)&Asl[r][k] = b4;
        }
#pragma unroll
        for (int p = 0; p < 8; p++) {
            int e8 = (p * 256 + tid) * 8;
            int n = e8 >> 7, k = e8 & 127;
            bf16x8 v = *(const bf16x8*)&BT[(size_t)(n0 + n) * K + kc + k];
            *(bf16x8*)&Bsl[n][k] = v;
        }
        __syncthreads();
        int ar = w * 16 + l15;
#pragma unroll
        for (int kt = 0; kt < 4; kt++) {
            bf16x8 a = *(const bf16x8*)&Asl[ar][kt * 32 + q * 8];
#pragma unroll
            for (int nt = 0; nt < 8; nt++) {
                bf16x8 b = *(const bf16x8*)&Bsl[nt * 16 + l15][kt * 32 + q * 8];
                acc[nt] = __builtin_amdgcn_mfma_f32_16x16x32_bf16(a, b, acc[nt], 0, 0, 0);
            }
        }
        __syncthreads();
    }
#pragma unroll
    for (int nt = 0; nt < 8; nt++) {
        int col = n0 + nt * 16 + l15;
        float bv = bias ? bias[col] : 0.0f;
#pragma unroll
        for (int reg = 0; reg < 4; reg++) {
            int row = m0 + w * 16 + q * 4 + reg;
            if (row < M) {
                float v = acc[nt][reg] + bv;
                if (act) v = silu_f(v);
                if (resid) v += resid[(size_t)row * 128 + (col & 127)];
                if (opq) {
                    *(bf16*)((char*)C + (size_t)row * PQ_STRIDE + col * 2) = (bf16)v;
                } else {
                    C[(size_t)row * Ntot + col] = v;
                }
            }
        }
    }
}

// ---------------------------------------------------------------------------
// Fused node MLP + next projection:
//   h = h + silu([h|agg] @ nw1 + nb1) @ nw2 + nb2
//   PQ = hnew @ PT + pbias   (written bf16, 512B rows)
// zeroA2=1: zero agg rows in place after reading (replaces mid-pipe memset).
// ---------------------------------------------------------------------------
__global__ __launch_bounds__(256) void k_node_mlp(
    float* __restrict__ A2,             // agg (zeroed in place if zeroA2)
    const bf16* __restrict__ B1T,       // nw1T [128][256]
    const float* __restrict__ b1,
    const bf16* __restrict__ B2T,       // nw2T [128][128]
    const float* __restrict__ b2,
    float* __restrict__ H,              // outh, in/out
    int M, int zeroA2,
    const bf16* __restrict__ PT,        // next proj [256][128]
    const float* __restrict__ pbias,    // 256 (eb1 in P half, 0 in Q half)
    char* __restrict__ PQout) {
    __shared__ __align__(16) bf16 Asl[64][136];
    __shared__ __align__(16) bf16 Bsl[128][136];
    int tid = threadIdx.x;
    int m0 = blockIdx.x * 64;
    int lane = tid & 63, w = tid >> 6;
    int q = lane >> 4, l15 = lane & 15;
    int ar = w * 16 + l15;

    f32x4 acc[8];
#pragma unroll
    for (int i = 0; i < 8; i++) acc[i] = (f32x4){0.f, 0.f, 0.f, 0.f};

    for (int kc = 0; kc < 256; kc += 128) {
        const float* Asrc = (kc == 0) ? H : A2;
#pragma unroll
        for (int p = 0; p < 8; p++) {
            int e4 = (p * 256 + tid) * 4;
            int r = e4 >> 7, k = e4 & 127;
            float4 v = {0.f, 0.f, 0.f, 0.f};
            int row = m0 + r;
            if (row < M) v = *(const float4*)&Asrc[(size_t)row * 128 + k];
            bf16x4 b4 = {(bf16)v.x, (bf16)v.y, (bf16)v.z, (bf16)v.w};
            *(bf16x4*)&Asl[r][k] = b4;
            if (kc == 128 && zeroA2 && row < M) {
                *(float4*)&A2[(size_t)row * 128 + k] = (float4){0.f, 0.f, 0.f, 0.f};
            }
        }
#pragma unroll
        for (int p = 0; p < 8; p++) {
            int e8 = (p * 256 + tid) * 8;
            int n = e8 >> 7, k = e8 & 127;
            bf16x8 v = *(const bf16x8*)&B1T[(size_t)n * 256 + kc + k];
            *(bf16x8*)&Bsl[n][k] = v;
        }
        __syncthreads();
#pragma unroll
        for (int kt = 0; kt < 4; kt++) {
            bf16x8 a = *(const bf16x8*)&Asl[ar][kt * 32 + q * 8];
#pragma unroll
            for (int nt = 0; nt < 8; nt++) {
                bf16x8 b = *(const bf16x8*)&Bsl[nt * 16 + l15][kt * 32 + q * 8];
                acc[nt] = __builtin_amdgcn_mfma_f32_16x16x32_bf16(a, b, acc[nt], 0, 0, 0);
            }
        }
        __syncthreads();
    }
#pragma unroll
    for (int nt = 0; nt < 8; nt++) {
        float bv = b1[nt * 16 + l15];
#pragma unroll
        for (int reg = 0; reg < 4; reg++) {
            int r = w * 16 + q * 4 + reg;
            Asl[r][nt * 16 + l15] = (bf16)silu_f(acc[nt][reg] + bv);
        }
    }
#pragma unroll
    for (int p = 0; p < 8; p++) {
        int e8 = (p * 256 + tid) * 8;
        int n = e8 >> 7, k = e8 & 127;
        *(bf16x8*)&Bsl[n][k] = *(const bf16x8*)&B2T[(size_t)n * 128 + k];
    }
    __syncthreads();
    f32x4 acc2[8];
#pragma unroll
    for (int i = 0; i < 8; i++) acc2[i] = (f32x4){0.f, 0.f, 0.f, 0.f};
#pragma unroll
    for (int kt = 0; kt < 4; kt++) {
        bf16x8 a = *(const bf16x8*)&Asl[ar][kt * 32 + q * 8];
#pragma unroll
        for (int nt = 0; nt < 8; nt++) {
            bf16x8 b = *(const bf16x8*)&Bsl[nt * 16 + l15][kt * 32 + q * 8];
            acc2[nt] = __builtin_amdgcn_mfma_f32_16x16x32_bf16(a, b, acc2[nt], 0, 0, 0);
        }
    }
    // residual add -> Hnew (kept in acc2)
#pragma unroll
    for (int nt = 0; nt < 8; nt++) {
        int col = nt * 16 + l15;
        float bv = b2[col];
#pragma unroll
        for (int reg = 0; reg < 4; reg++) {
            int row = m0 + w * 16 + q * 4 + reg;
            if (row < M) {
                float hv = H[(size_t)row * 128 + col] + acc2[nt][reg] + bv;
                H[(size_t)row * 128 + col] = hv;
                acc2[nt][reg] = hv;
            }
        }
    }
    __syncthreads();   // all GEMM2 LDS reads done
    // Hnew -> Asl bf16 A-tile for the fused projection
#pragma unroll
    for (int nt = 0; nt < 8; nt++) {
#pragma unroll
        for (int reg = 0; reg < 4; reg++) {
            int r = w * 16 + q * 4 + reg;
            Asl[r][nt * 16 + l15] = (bf16)acc2[nt][reg];
        }
    }
    // fused projection: PQ = Hnew @ PT + pbias, two 128-col halves
    for (int half = 0; half < 2; half++) {
#pragma unroll
        for (int p = 0; p < 8; p++) {
            int e8 = (p * 256 + tid) * 8;
            int n = e8 >> 7, k = e8 & 127;
            *(bf16x8*)&Bsl[n][k] = *(const bf16x8*)&PT[(size_t)(half * 128 + n) * 128 + k];
        }
        __syncthreads();
        f32x4 accp[8];
#pragma unroll
        for (int i = 0; i < 8; i++) accp[i] = (f32x4){0.f, 0.f, 0.f, 0.f};
#pragma unroll
        for (int kt = 0; kt < 4; kt++) {
            bf16x8 a = *(const bf16x8*)&Asl[ar][kt * 32 + q * 8];
#pragma unroll
            for (int nt = 0; nt < 8; nt++) {
                bf16x8 b = *(const bf16x8*)&Bsl[nt * 16 + l15][kt * 32 + q * 8];
                accp[nt] = __builtin_amdgcn_mfma_f32_16x16x32_bf16(a, b, accp[nt], 0, 0, 0);
            }
        }
#pragma unroll
        for (int nt = 0; nt < 8; nt++) {
            int colg = half * 128 + nt * 16 + l15;
            float bv = pbias[colg];
#pragma unroll
            for (int reg = 0; reg < 4; reg++) {
                int row = m0 + w * 16 + q * 4 + reg;
                if (row < M) {
                    *(bf16*)(PQout + (size_t)row * PQ_STRIDE + colg * 2) =
                        (bf16)(accp[nt][reg] + bv);
                }
            }
        }
        __syncthreads();
    }
}

// ---------------------------------------------------------------------------
// Persistent fused GCL edge kernel: 512 threads, 128 sorted edges/tile.
// (Round-8 structure; eb1 folded into P; rcp-based silu/sigmoid.)
// ---------------------------------------------------------------------------
#define NTILES (E_N / 128)

__global__ __launch_bounds__(512, 4) void k_edge_gcl(
    const int* __restrict__ srow, const int* __restrict__ scol,
    const char* __restrict__ PQ,
    const float* __restrict__ ea2, const float* __restrict__ w1c,
    const bf16* __restrict__ ew2T,
    const float* __restrict__ eb2, const float* __restrict__ aw,
    const float* __restrict__ ab, float* __restrict__ agg) {
    __shared__ __align__(16) bf16 Asl[128][136];   // A-tile; reused as bf16 Fsl
    __shared__ __align__(16) bf16 Bsl[128][136];   // persistent weight tile
    __shared__ int rows_s[128];
    __shared__ int cols_s[128];
    __shared__ float ra_s[128], aa_s[128];
    int tid = threadIdx.x;
    int lane = tid & 63, w = tid >> 6, q = lane >> 4, l15 = lane & 15;
    int j = (tid & 31) * 4;   // fixed column group per thread
    int eslot = tid >> 5;     // edge sub-slot (0..15)

    // stage B once
#pragma unroll
    for (int p = 0; p < 4; p++) {
        int e8 = (p * 512 + tid) * 8;
        int n = e8 >> 7, k = e8 & 127;
        *(bf16x8*)&Bsl[n][k] = *(const bf16x8*)&ew2T[n * 128 + k];
    }
    float4 w0r = *(const float4*)&w1c[j];
    float4 w1r = *(const float4*)&w1c[128 + j];
    float b2v[8], awv[8];
#pragma unroll
    for (int nt = 0; nt < 8; nt++) {
        b2v[nt] = eb2[nt * 16 + l15];
        awv[nt] = aw[nt * 16 + l15];
    }
    float ab0 = ab[0];

    for (int t = blockIdx.x; t < NTILES; t += gridDim.x) {
        int e0 = t * 128;
        __syncthreads();   // prev tile's seg-reduce done (Asl/rows_s free)
        if (tid < 128) {
            int e = e0 + tid;
            rows_s[tid] = srow[e];
            cols_s[tid] = scol[e];
            float2 rr = *(const float2*)&ea2[(size_t)e * 2];
            ra_s[tid] = rr.x;
            aa_s[tid] = rr.y;
        }
        __syncthreads();
        // stage A: issue all 16 gathers, then compute
        bf16x4 pb[8];
        bf16x4 qb[8];
#pragma unroll
        for (int p = 0; p < 8; p++) {
            int el = p * 16 + eslot;
            int row = rows_s[el], col = cols_s[el];
            pb[p] = *(const bf16x4*)(PQ + (size_t)row * PQ_STRIDE + j * 2);
            qb[p] = *(const bf16x4*)(PQ + (size_t)col * PQ_STRIDE + 256 + j * 2);
        }
#pragma unroll
        for (int p = 0; p < 8; p++) {
            int el = p * 16 + eslot;
            float ra = ra_s[el], aa = aa_s[el];
            float zx = (float)pb[p][0] + (float)qb[p][0];
            float zy = (float)pb[p][1] + (float)qb[p][1];
            float zz = (float)pb[p][2] + (float)qb[p][2];
            float zw = (float)pb[p][3] + (float)qb[p][3];
            zx = fmaf(aa, w1r.x, fmaf(ra, w0r.x, zx));
            zy = fmaf(aa, w1r.y, fmaf(ra, w0r.y, zy));
            zz = fmaf(aa, w1r.z, fmaf(ra, w0r.z, zz));
            zw = fmaf(aa, w1r.w, fmaf(ra, w0r.w, zw));
            bf16x4 b4 = {(bf16)silu_f(zx), (bf16)silu_f(zy),
                         (bf16)silu_f(zz), (bf16)silu_f(zw)};
            *(bf16x4*)&Asl[el][j] = b4;
        }
        __syncthreads();
        f32x4 acc[8];
#pragma unroll
        for (int i = 0; i < 8; i++) acc[i] = (f32x4){0.f, 0.f, 0.f, 0.f};
        int ar = w * 16 + l15;
#pragma unroll
        for (int kt = 0; kt < 4; kt++) {
            bf16x8 a = *(const bf16x8*)&Asl[ar][kt * 32 + q * 8];
#pragma unroll
            for (int nt = 0; nt < 8; nt++) {
                bf16x8 b = *(const bf16x8*)&Bsl[nt * 16 + l15][kt * 32 + q * 8];
                acc[nt] = __builtin_amdgcn_mfma_f32_16x16x32_bf16(a, b, acc[nt], 0, 0, 0);
            }
        }
        // epilogue in regs: silu + attention dot
        float partial[4] = {0.f, 0.f, 0.f, 0.f};
#pragma unroll
        for (int nt = 0; nt < 8; nt++) {
#pragma unroll
            for (int reg = 0; reg < 4; reg++) {
                float mv = silu_f(acc[nt][reg] + b2v[nt]);
                acc[nt][reg] = mv;
                partial[reg] += mv * awv[nt];
            }
        }
        float scale[4];
#pragma unroll
        for (int reg = 0; reg < 4; reg++) {
            float s = partial[reg];
            s += __shfl_xor(s, 1, 16);
            s += __shfl_xor(s, 2, 16);
            s += __shfl_xor(s, 4, 16);
            s += __shfl_xor(s, 8, 16);
            scale[reg] = sigmoid_f(s + ab0) * 0.01f;
        }
        __syncthreads();   // all Asl MFMA reads done -> overlay Fsl (bf16)
#pragma unroll
        for (int reg = 0; reg < 4; reg++) {
            int er = w * 16 + q * 4 + reg;
            float sc = scale[reg];
#pragma unroll
            for (int nt = 0; nt < 8; nt++) {
                Asl[er][nt * 16 + l15] = (bf16)(acc[nt][reg] * sc);
            }
        }
        __syncthreads();
        // segmented reduction over sorted-row runs: quarter of 32 edges each
        int col = tid & 127, quarter = tid >> 7;
        int es = quarter * 32, ee = es + 32;
        float sum = 0.f;
        for (int el = es; el < ee; ++el) {
            sum += (float)Asl[el][col];
            int r = rows_s[el];
            int nxt = (el + 1 < ee) ? rows_s[el + 1] : -1;
            if (r != nxt) {
                atomicAdd(&agg[(size_t)r * 128 + col], sum);
                sum = 0.f;
            }
        }
    }
}

// ---------------------------------------------------------------------------
// Persistent fused coord-update edge kernel (cb1 folded into P)
// ---------------------------------------------------------------------------
__global__ __launch_bounds__(512, 4) void k_edge_coord(
    const int* __restrict__ srow, const int* __restrict__ scol,
    const char* __restrict__ PQ,
    const float* __restrict__ ea2, const float* __restrict__ c1c,
    const bf16* __restrict__ cw2T,
    const float* __restrict__ cb2, const float* __restrict__ cw3,
    const float* __restrict__ cd, float* __restrict__ xagg) {
    __shared__ __align__(16) bf16 Asl[128][136];
    __shared__ __align__(16) bf16 Bsl[128][136];
    __shared__ int rows_s[128];
    __shared__ int cols_s[128];
    __shared__ float ra_s[128], aa_s[128];
    __shared__ float cds[384];
    __shared__ float Ssl[128];
    int tid = threadIdx.x;
    int lane = tid & 63, w = tid >> 6, q = lane >> 4, l15 = lane & 15;
    int j = (tid & 31) * 4;
    int eslot = tid >> 5;

#pragma unroll
    for (int p = 0; p < 4; p++) {
        int e8 = (p * 512 + tid) * 8;
        int n = e8 >> 7, k = e8 & 127;
        *(bf16x8*)&Bsl[n][k] = *(const bf16x8*)&cw2T[n * 128 + k];
    }
    float4 w0r = *(const float4*)&c1c[j];
    float4 w1r = *(const float4*)&c1c[128 + j];
    float b2v[8], w3v[8];
#pragma unroll
    for (int nt = 0; nt < 8; nt++) {
        b2v[nt] = cb2[nt * 16 + l15];
        w3v[nt] = cw3[nt * 16 + l15];
    }

    for (int t = blockIdx.x; t < NTILES; t += gridDim.x) {
        int e0 = t * 128;
        __syncthreads();
        if (tid < 128) {
            int e = e0 + tid;
            rows_s[tid] = srow[e];
            cols_s[tid] = scol[e];
            float2 rr = *(const float2*)&ea2[(size_t)e * 2];
            ra_s[tid] = rr.x;
            aa_s[tid] = rr.y;
        }
        if (tid < 384) cds[tid] = cd[(size_t)e0 * 3 + tid];
        __syncthreads();
        bf16x4 pb[8];
        bf16x4 qb[8];
#pragma unroll
        for (int p = 0; p < 8; p++) {
            int el = p * 16 + eslot;
            int row = rows_s[el], col = cols_s[el];
            pb[p] = *(const bf16x4*)(PQ + (size_t)row * PQ_STRIDE + j * 2);
            qb[p] = *(const bf16x4*)(PQ + (size_t)col * PQ_STRIDE + 256 + j * 2);
        }
#pragma unroll
        for (int p = 0; p < 8; p++) {
            int el = p * 16 + eslot;
            float ra = ra_s[el], aa = aa_s[el];
            float zx = (float)pb[p][0] + (float)qb[p][0];
            float zy = (float)pb[p][1] + (float)qb[p][1];
            float zz = (float)pb[p][2] + (float)qb[p][2];
            float zw = (float)pb[p][3] + (float)qb[p][3];
            zx = fmaf(aa, w1r.x, fmaf(ra, w0r.x, zx));
            zy = fmaf(aa, w1r.y, fmaf(ra, w0r.y, zy));
            zz = fmaf(aa, w1r.z, fmaf(ra, w0r.z, zz));
            zw = fmaf(aa, w1r.w, fmaf(ra, w0r.w, zw));
            bf16x4 b4 = {(bf16)silu_f(zx), (bf16)silu_f(zy),
                         (bf16)silu_f(zz), (bf16)silu_f(zw)};
            *(bf16x4*)&Asl[el][j] = b4;
        }
        __syncthreads();
        f32x4 acc[8];
#pragma unroll
        for (int i = 0; i < 8; i++) acc[i] = (f32x4){0.f, 0.f, 0.f, 0.f};
        int ar = w * 16 + l15;
#pragma unroll
        for (int kt = 0; kt < 4; kt++) {
            bf16x8 a = *(const bf16x8*)&Asl[ar][kt * 32 + q * 8];
#pragma unroll
            for (int nt = 0; nt < 8; nt++) {
                bf16x8 b = *(const bf16x8*)&Bsl[nt * 16 + l15][kt * 32 + q * 8];
                acc[nt] = __builtin_amdgcn_mfma_f32_16x16x32_bf16(a, b, acc[nt], 0, 0, 0);
            }
        }
        float partial[4] = {0.f, 0.f, 0.f, 0.f};
#pragma unroll
        for (int nt = 0; nt < 8; nt++) {
#pragma unroll
            for (int reg = 0; reg < 4; reg++) {
                float tv = silu_f(acc[nt][reg] + b2v[nt]);
                partial[reg] += tv * w3v[nt];
            }
        }
#pragma unroll
        for (int reg = 0; reg < 4; reg++) {
            float s = partial[reg];
            s += __shfl_xor(s, 1, 16);
            s += __shfl_xor(s, 2, 16);
            s += __shfl_xor(s, 4, 16);
            s += __shfl_xor(s, 8, 16);
            if (l15 == 0) Ssl[w * 16 + q * 4 + reg] = s * 0.01f;
        }
        __syncthreads();
        // segmented reduce of trans = cd*s over sorted-row runs (48 thr x 8)
        if (tid < 48) {
            int d = tid % 3, chunk = tid / 3;
            int es = chunk * 8, ee = es + 8;
            float sum = 0.f;
            for (int el = es; el < ee; ++el) {
                sum += cds[el * 3 + d] * Ssl[el];
                int r = rows_s[el];
                int nxt = (el + 1 < ee) ? rows_s[el + 1] : -1;
                if (r != nxt) {
                    atomicAdd(&xagg[(size_t)r * 3 + d], sum);
                    sum = 0.f;
                }
            }
        }
    }
}

__global__ void k_finalx(const float* __restrict__ x, const float* __restrict__ xagg,
                         float* __restrict__ outx) {
    int i = blockIdx.x * 256 + threadIdx.x;
    if (i < V_N * 3) outx[i] = x[i] + xagg[i];
}

// ---------------------------------------------------------------------------
extern "C" void kernel_launch(void* const* d_in, const int* in_sizes, int n_in,
                              void* d_out, int out_size, void* d_ws, size_t ws_size,
                              hipStream_t stream) {
    const float* h = (const float*)d_in[0];
    const float* x = (const float*)d_in[1];
    const int* ei = (const int*)d_in[2];
    const float* eattr = (const float*)d_in[3];
    const float* ew1 = (const float*)d_in[4];
    const float* eb1 = (const float*)d_in[5];
    const float* ew2 = (const float*)d_in[6];
    const float* eb2 = (const float*)d_in[7];
    const float* aw = (const float*)d_in[8];
    const float* ab = (const float*)d_in[9];
    const float* nw1 = (const float*)d_in[10];
    const float* nb1 = (const float*)d_in[11];
    const float* nw2 = (const float*)d_in[12];
    const float* nb2 = (const float*)d_in[13];
    const float* cw1 = (const float*)d_in[14];
    const float* cb1 = (const float*)d_in[15];
    const float* cw2 = (const float*)d_in[16];
    const float* cb2 = (const float*)d_in[17];
    const float* cw3 = (const float*)d_in[18];

    char* ws = (char*)d_ws;
    size_t off_b = 0;
    auto alloc = [&](size_t b) {
        size_t o = off_b;
        off_b += (b + 255) & ~(size_t)255;
        return o;
    };
    float* cd = (float*)(ws + alloc((size_t)E_N * 3 * 4));
    float* ea2 = (float*)(ws + alloc((size_t)E_N * 2 * 4));
    char* PQ = (char*)(ws + alloc((size_t)V_N * PQ_STRIDE));
    float* agg = (float*)(ws + alloc((size_t)V_N * 128 * 4));
    float* xagg = (float*)(ws + alloc((size_t)V_N * 3 * 4));
    bf16* projT = (bf16*)(ws + alloc(2 * 256 * 128 * 2));
    bf16* ew2T = (bf16*)(ws + alloc(2 * 128 * 128 * 2));
    bf16* nw1T = (bf16*)(ws + alloc(2 * 128 * 256 * 2));
    bf16* nw2T = (bf16*)(ws + alloc(2 * 128 * 128 * 2));
    bf16* cprojT = (bf16*)(ws + alloc(256 * 128 * 2));
    bf16* cw2T = (bf16*)(ws + alloc(128 * 128 * 2));
    float* biasPQ = (float*)(ws + alloc(2 * 256 * 4));
    float* biasCPQ = (float*)(ws + alloc(256 * 4));
    int* cnt = (int*)(ws + alloc((size_t)V_N * 4));
    int* offv = (int*)(ws + alloc((size_t)V_N * 4));
    int* srow = (int*)(ws + alloc((size_t)E_N * 4));
    int* scol = (int*)(ws + alloc((size_t)E_N * 4));
    int* perm = (int*)(ws + alloc((size_t)E_N * 4));

    float* outh = (float*)d_out;
    float* outx = outh + (size_t)V_N * 128;

    hipMemcpyAsync(outh, h, (size_t)V_N * 128 * 4, hipMemcpyDeviceToDevice, stream);
    k_weights<<<964, 256, 0, stream>>>(ew1, ew2, nw1, nw2, cw1, cw2, eb1, cb1,
                                       projT, ew2T, nw1T, nw2T, cprojT, cw2T,
                                       biasPQ, biasCPQ);
    // counting sort of edges by row
    hipMemsetAsync(cnt, 0, (size_t)V_N * 4, stream);
    k_hist<<<(E_N + 255) / 256, 256, 0, stream>>>(ei, cnt);
    k_scan<<<1, 1024, 0, stream>>>(cnt, offv);
    k_scatter<<<(E_N + 255) / 256, 256, 0, stream>>>(ei, offv, srow, scol, perm);
    k_edgeprep2<<<(E_N + 255) / 256, 256, 0, stream>>>(perm, srow, scol, x, eattr, cd, ea2);
    hipMemsetAsync(xagg, 0, (size_t)V_N * 3 * 4, stream);
    hipMemsetAsync(agg, 0, (size_t)V_N * 128 * 4, stream);

    int mblocks = (V_N + 63) / 64;
    // layer 0: standalone projection (bias-folded)
    dim3 gproj(mblocks, 2);
    k_node_gemm<<<gproj, 256, 0, stream>>>(outh, nullptr, projT, biasPQ, nullptr,
                                           (float*)PQ, V_N, 128, 256, 0, 1);
    k_edge_gcl<<<512, 512, 0, stream>>>(
        srow, scol, PQ, ea2, ew1 + 256 * 128,
        ew2T, eb2, aw, ab, agg);
    // node MLP 0 (zeroes agg in place) + fused projection for layer 1
    k_node_mlp<<<mblocks, 256, 0, stream>>>(agg, nw1T, nb1, nw2T, nb2, outh, V_N, 1,
                                            projT + 256 * 128, biasPQ + 256, PQ);
    k_edge_gcl<<<512, 512, 0, stream>>>(
        srow, scol, PQ, ea2, ew1 + (size_t)1 * 258 * 128 + 256 * 128,
        ew2T + 128 * 128, eb2 + 128, aw + 128, ab + 1, agg);
    // node MLP 1 + fused coord projection
    k_node_mlp<<<mblocks, 256, 0, stream>>>(agg, nw1T + 128 * 256, nb1 + 128,
                                            nw2T + 128 * 128, nb2 + 128, outh, V_N, 0,
                                            cprojT, biasCPQ, PQ);
    k_edge_coord<<<512, 512, 0, stream>>>(srow, scol, PQ, ea2, cw1 + 256 * 128,
                                          cw2T, cb2, cw3, cd, xagg);
    k_finalx<<<(V_N * 3 + 255) / 256, 256, 0, stream>>>(x, xagg, outx);
}

// Round 12
// 765.707 us; speedup vs baseline: 2.3065x; 1.0078x over previous
//
#include <hip/hip_runtime.h>

#define V_N 50000
#define E_N 800000
#define H_N 128

typedef __bf16 bf16;
typedef bf16 bf16x4 __attribute__((ext_vector_type(4)));
typedef bf16 bf16x8 __attribute__((ext_vector_type(8)));
typedef float f32x4 __attribute__((ext_vector_type(4)));

// PQ all-bf16 row layout: 512 bytes/node = 128 bf16 (P, bias-folded) + 128 bf16 (Q)
#define PQ_STRIDE 512

// Fast silu/sigmoid: v_rcp_f32 instead of the IEEE divide sequence.
__device__ __forceinline__ float silu_f(float x) {
    return x * __builtin_amdgcn_rcpf(1.0f + __expf(-x));
}
__device__ __forceinline__ float sigmoid_f(float x) {
    return __builtin_amdgcn_rcpf(1.0f + __expf(-x));
}

// ---------------------------------------------------------------------------
// Weight prep: transpose all GEMM weights to [N][K] bf16 + build PQ bias
// tables (eb1/cb1 folded into the P half of the projection output).
// ---------------------------------------------------------------------------
__global__ void k_weights(const float* __restrict__ ew1, const float* __restrict__ ew2,
                          const float* __restrict__ nw1, const float* __restrict__ nw2,
                          const float* __restrict__ cw1, const float* __restrict__ cw2,
                          const float* __restrict__ eb1, const float* __restrict__ cb1,
                          bf16* __restrict__ projT, bf16* __restrict__ ew2T,
                          bf16* __restrict__ nw1T, bf16* __restrict__ nw2T,
                          bf16* __restrict__ cprojT, bf16* __restrict__ cw2T,
                          float* __restrict__ biasPQ, float* __restrict__ biasCPQ) {
    int idx = blockIdx.x * 256 + threadIdx.x;
    if (idx < 65536) {                       // projT: 2 layers x [256][128]
        int l = idx >> 15, rem = idx & 32767;
        int n = rem >> 7, k = rem & 127;
        const float* W = ew1 + l * 258 * 128;
        projT[idx] = (bf16)((n < 128) ? W[k * 128 + n] : W[(128 + k) * 128 + (n - 128)]);
    } else if (idx < 98304) {                // ew2T: 2 x [128][128]
        int r = idx - 65536;
        int l = r >> 14, rem = r & 16383;
        int n = rem >> 7, k = rem & 127;
        ew2T[r] = (bf16)(ew2[l * 16384 + k * 128 + n]);
    } else if (idx < 163840) {               // nw1T: 2 x [128][256]
        int r = idx - 98304;
        int l = r >> 15, rem = r & 32767;
        int n = rem >> 8, k = rem & 255;
        nw1T[r] = (bf16)(nw1[l * 32768 + k * 128 + n]);
    } else if (idx < 196608) {               // nw2T: 2 x [128][128]
        int r = idx - 163840;
        int l = r >> 14, rem = r & 16383;
        int n = rem >> 7, k = rem & 127;
        nw2T[r] = (bf16)(nw2[l * 16384 + k * 128 + n]);
    } else if (idx < 229376) {               // cprojT: [256][128]
        int r = idx - 196608;
        int n = r >> 7, k = r & 127;
        cprojT[r] = (bf16)((n < 128) ? cw1[k * 128 + n] : cw1[(128 + k) * 128 + (n - 128)]);
    } else if (idx < 245760) {               // cw2T: [128][128]
        int r = idx - 229376;
        int n = r >> 7, k = r & 127;
        cw2T[r] = (bf16)(cw2[k * 128 + n]);
    } else if (idx < 246272) {               // biasPQ: 2 layers x [256]
        int r = idx - 245760;
        int l = r >> 8, c = r & 255;
        biasPQ[r] = (c < 128) ? eb1[l * 128 + c] : 0.0f;
    } else if (idx < 246528) {               // biasCPQ: [256]
        int c = idx - 246272;
        biasCPQ[c] = (c < 128) ? cb1[c] : 0.0f;
    }
}

// ---------------------------------------------------------------------------
// Counting sort of edges by destination row (ei[0][e]).
// ---------------------------------------------------------------------------
__global__ void k_hist(const int* __restrict__ ei, int* __restrict__ cnt) {
    int e = blockIdx.x * 256 + threadIdx.x;
    if (e < E_N) atomicAdd(&cnt[ei[e]], 1);
}

__global__ __launch_bounds__(1024) void k_scan(const int* __restrict__ cnt,
                                               int* __restrict__ off) {
    __shared__ int wsum[16];
    __shared__ int wscan[16];
    __shared__ int carry_s;
    int tid = threadIdx.x;
    int lane = tid & 63, wid = tid >> 6;
    if (tid == 0) carry_s = 0;
    __syncthreads();
    for (int base = 0; base < V_N; base += 1024) {
        int carry = carry_s;
        int i = base + tid;
        int v = (i < V_N) ? cnt[i] : 0;
        int val = v;
#pragma unroll
        for (int d = 1; d < 64; d <<= 1) {
            int t = __shfl_up(val, d, 64);
            if (lane >= d) val += t;
        }
        if (lane == 63) wsum[wid] = val;
        __syncthreads();
        if (tid == 0) {
            int s = 0;
#pragma unroll
            for (int k = 0; k < 16; k++) { s += wsum[k]; wscan[k] = s; }
        }
        __syncthreads();
        int wbase = wid ? wscan[wid - 1] : 0;
        if (i < V_N) off[i] = carry + wbase + val - v;
        __syncthreads();
        if (tid == 0) carry_s = carry + wscan[15];
        __syncthreads();
    }
}

__global__ void k_scatter(const int* __restrict__ ei, int* __restrict__ off,
                          int* __restrict__ srow, int* __restrict__ scol,
                          int* __restrict__ perm) {
    int e = blockIdx.x * 256 + threadIdx.x;
    if (e >= E_N) return;
    int r = ei[e], c = ei[E_N + e];
    int p = atomicAdd(&off[r], 1);
    srow[p] = r;
    scol[p] = c;
    perm[p] = e;
}

__global__ void k_edgeprep2(const int* __restrict__ perm, const int* __restrict__ srow,
                            const int* __restrict__ scol, const float* __restrict__ x,
                            const float* __restrict__ eattr,
                            float* __restrict__ cd, float* __restrict__ ea2) {
    int p = blockIdx.x * 256 + threadIdx.x;
    if (p >= E_N) return;
    int e = perm[p];
    int r = srow[p], c = scol[p];
    float dx = x[r * 3 + 0] - x[c * 3 + 0];
    float dy = x[r * 3 + 1] - x[c * 3 + 1];
    float dz = x[r * 3 + 2] - x[c * 3 + 2];
    float rad = dx * dx + dy * dy + dz * dz;
    float inv = 1.0f / (sqrtf(rad + 1e-8f) + 1.0f);
    cd[p * 3 + 0] = dx * inv;
    cd[p * 3 + 1] = dy * inv;
    cd[p * 3 + 2] = dz * inv;
    ea2[p * 2 + 0] = rad;
    ea2[p * 2 + 1] = eattr[e];
}

// ---------------------------------------------------------------------------
// Generic node-level GEMM. opq=1 writes the all-bf16 PQ layout (512B rows).
// ---------------------------------------------------------------------------
__global__ __launch_bounds__(256) void k_node_gemm(
    const float* __restrict__ A1, const float* __restrict__ A2,
    const bf16* __restrict__ BT, const float* __restrict__ bias,
    const float* __restrict__ resid, float* __restrict__ C,
    int M, int K, int Ntot, int act, int opq) {
    __shared__ __align__(16) bf16 Asl[64][136];
    __shared__ __align__(16) bf16 Bsl[128][136];
    int tid = threadIdx.x;
    int m0 = blockIdx.x * 64;
    int n0 = blockIdx.y * 128;
    int lane = tid & 63, w = tid >> 6;
    int q = lane >> 4, l15 = lane & 15;

    f32x4 acc[8];
#pragma unroll
    for (int i = 0; i < 8; i++) acc[i] = (f32x4){0.f, 0.f, 0.f, 0.f};

    for (int kc = 0; kc < K; kc += 128) {
        const float* Asrc = (kc == 0) ? A1 : A2;
#pragma unroll
        for (int p = 0; p < 8; p++) {
            int e4 = (p * 256 + tid) * 4;
            int r = e4 >> 7, k = e4 & 127;
            float4 v = {0.f, 0.f, 0.f, 0.f};
            int row = m0 + r;
            if (row < M) v = *(const float4*)&Asrc[(size_t)row * 128 + k];
            bf16x4 b4 = {(bf16)v.x, (bf16)v.y, (bf16)v.z, (bf16)v.w};
            *(bf16x4*)&Asl[r][k] = b4;
        }
#pragma unroll
        for (int p = 0; p < 8; p++) {
            int e8 = (p * 256 + tid) * 8;
            int n = e8 >> 7, k = e8 & 127;
            bf16x8 v = *(const bf16x8*)&BT[(size_t)(n0 + n) * K + kc + k];
            *(bf16x8*)&Bsl[n][k] = v;
        }
        __syncthreads();
        int ar = w * 16 + l15;
#pragma unroll
        for (int kt = 0; kt < 4; kt++) {
            bf16x8 a = *(const bf16x8*)&Asl[ar][kt * 32 + q * 8];
#pragma unroll
            for (int nt = 0; nt < 8; nt++) {
                bf16x8 b = *(const bf16x8*)&Bsl[nt * 16 + l15][kt * 32 + q * 8];
                acc[nt] = __builtin_amdgcn_mfma_f32_16x16x32_bf16(a, b, acc[nt], 0, 0, 0);
            }
        }
        __syncthreads();
    }
#pragma unroll
    for (int nt = 0; nt < 8; nt++) {
        int col = n0 + nt * 16 + l15;
        float bv = bias ? bias[col] : 0.0f;
#pragma unroll
        for (int reg = 0; reg < 4; reg++) {
            int row = m0 + w * 16 + q * 4 + reg;
            if (row < M) {
                float v = acc[nt][reg] + bv;
                if (act) v = silu_f(v);
                if (resid) v += resid[(size_t)row * 128 + (col & 127)];
                if (opq) {
                    *(bf16*)((char*)C + (size_t)row * PQ_STRIDE + col * 2) = (bf16)v;
                } else {
                    C[(size_t)row * Ntot + col] = v;
                }
            }
        }
    }
}

// ---------------------------------------------------------------------------
// Fused node MLP + next projection.
// ---------------------------------------------------------------------------
__global__ __launch_bounds__(256) void k_node_mlp(
    float* __restrict__ A2,             // agg (zeroed in place if zeroA2)
    const bf16* __restrict__ B1T,       // nw1T [128][256]
    const float* __restrict__ b1,
    const bf16* __restrict__ B2T,       // nw2T [128][128]
    const float* __restrict__ b2,
    float* __restrict__ H,              // outh, in/out
    int M, int zeroA2,
    const bf16* __restrict__ PT,        // next proj [256][128]
    const float* __restrict__ pbias,    // 256 (eb1 in P half, 0 in Q half)
    char* __restrict__ PQout) {
    __shared__ __align__(16) bf16 Asl[64][136];
    __shared__ __align__(16) bf16 Bsl[128][136];
    int tid = threadIdx.x;
    int m0 = blockIdx.x * 64;
    int lane = tid & 63, w = tid >> 6;
    int q = lane >> 4, l15 = lane & 15;
    int ar = w * 16 + l15;

    f32x4 acc[8];
#pragma unroll
    for (int i = 0; i < 8; i++) acc[i] = (f32x4){0.f, 0.f, 0.f, 0.f};

    for (int kc = 0; kc < 256; kc += 128) {
        const float* Asrc = (kc == 0) ? H : A2;
#pragma unroll
        for (int p = 0; p < 8; p++) {
            int e4 = (p * 256 + tid) * 4;
            int r = e4 >> 7, k = e4 & 127;
            float4 v = {0.f, 0.f, 0.f, 0.f};
            int row = m0 + r;
            if (row < M) v = *(const float4*)&Asrc[(size_t)row * 128 + k];
            bf16x4 b4 = {(bf16)v.x, (bf16)v.y, (bf16)v.z, (bf16)v.w};
            *(bf16x4*)&Asl[r][k] = b4;
            if (kc == 128 && zeroA2 && row < M) {
                *(float4*)&A2[(size_t)row * 128 + k] = (float4){0.f, 0.f, 0.f, 0.f};
            }
        }
#pragma unroll
        for (int p = 0; p < 8; p++) {
            int e8 = (p * 256 + tid) * 8;
            int n = e8 >> 7, k = e8 & 127;
            bf16x8 v = *(const bf16x8*)&B1T[(size_t)n * 256 + kc + k];
            *(bf16x8*)&Bsl[n][k] = v;
        }
        __syncthreads();
#pragma unroll
        for (int kt = 0; kt < 4; kt++) {
            bf16x8 a = *(const bf16x8*)&Asl[ar][kt * 32 + q * 8];
#pragma unroll
            for (int nt = 0; nt < 8; nt++) {
                bf16x8 b = *(const bf16x8*)&Bsl[nt * 16 + l15][kt * 32 + q * 8];
                acc[nt] = __builtin_amdgcn_mfma_f32_16x16x32_bf16(a, b, acc[nt], 0, 0, 0);
            }
        }
        __syncthreads();
    }
#pragma unroll
    for (int nt = 0; nt < 8; nt++) {
        float bv = b1[nt * 16 + l15];
#pragma unroll
        for (int reg = 0; reg < 4; reg++) {
            int r = w * 16 + q * 4 + reg;
            Asl[r][nt * 16 + l15] = (bf16)silu_f(acc[nt][reg] + bv);
        }
    }
#pragma unroll
    for (int p = 0; p < 8; p++) {
        int e8 = (p * 256 + tid) * 8;
        int n = e8 >> 7, k = e8 & 127;
        *(bf16x8*)&Bsl[n][k] = *(const bf16x8*)&B2T[(size_t)n * 128 + k];
    }
    __syncthreads();
    f32x4 acc2[8];
#pragma unroll
    for (int i = 0; i < 8; i++) acc2[i] = (f32x4){0.f, 0.f, 0.f, 0.f};
#pragma unroll
    for (int kt = 0; kt < 4; kt++) {
        bf16x8 a = *(const bf16x8*)&Asl[ar][kt * 32 + q * 8];
#pragma unroll
        for (int nt = 0; nt < 8; nt++) {
            bf16x8 b = *(const bf16x8*)&Bsl[nt * 16 + l15][kt * 32 + q * 8];
            acc2[nt] = __builtin_amdgcn_mfma_f32_16x16x32_bf16(a, b, acc2[nt], 0, 0, 0);
        }
    }
    // residual add -> Hnew (kept in acc2)
#pragma unroll
    for (int nt = 0; nt < 8; nt++) {
        int col = nt * 16 + l15;
        float bv = b2[col];
#pragma unroll
        for (int reg = 0; reg < 4; reg++) {
            int row = m0 + w * 16 + q * 4 + reg;
            if (row < M) {
                float hv = H[(size_t)row * 128 + col] + acc2[nt][reg] + bv;
                H[(size_t)row * 128 + col] = hv;
                acc2[nt][reg] = hv;
            }
        }
    }
    __syncthreads();   // all GEMM2 LDS reads done
#pragma unroll
    for (int nt = 0; nt < 8; nt++) {
#pragma unroll
        for (int reg = 0; reg < 4; reg++) {
            int r = w * 16 + q * 4 + reg;
            Asl[r][nt * 16 + l15] = (bf16)acc2[nt][reg];
        }
    }
    // fused projection: PQ = Hnew @ PT + pbias, two 128-col halves
    for (int half = 0; half < 2; half++) {
#pragma unroll
        for (int p = 0; p < 8; p++) {
            int e8 = (p * 256 + tid) * 8;
            int n = e8 >> 7, k = e8 & 127;
            *(bf16x8*)&Bsl[n][k] = *(const bf16x8*)&PT[(size_t)(half * 128 + n) * 128 + k];
        }
        __syncthreads();
        f32x4 accp[8];
#pragma unroll
        for (int i = 0; i < 8; i++) accp[i] = (f32x4){0.f, 0.f, 0.f, 0.f};
#pragma unroll
        for (int kt = 0; kt < 4; kt++) {
            bf16x8 a = *(const bf16x8*)&Asl[ar][kt * 32 + q * 8];
#pragma unroll
            for (int nt = 0; nt < 8; nt++) {
                bf16x8 b = *(const bf16x8*)&Bsl[nt * 16 + l15][kt * 32 + q * 8];
                accp[nt] = __builtin_amdgcn_mfma_f32_16x16x32_bf16(a, b, accp[nt], 0, 0, 0);
            }
        }
#pragma unroll
        for (int nt = 0; nt < 8; nt++) {
            int colg = half * 128 + nt * 16 + l15;
            float bv = pbias[colg];
#pragma unroll
            for (int reg = 0; reg < 4; reg++) {
                int row = m0 + w * 16 + q * 4 + reg;
                if (row < M) {
                    *(bf16*)(PQout + (size_t)row * PQ_STRIDE + colg * 2) =
                        (bf16)(accp[nt][reg] + bv);
                }
            }
        }
        __syncthreads();
    }
}

// ---------------------------------------------------------------------------
// Persistent fused GCL edge kernel: 512 threads, 128 sorted edges/tile.
// Meta double-buffered (one fewer barrier/tile); transposed FslT reduce
// scratch read via ds_read_b128 (4 loads/thread instead of 32 u16 reads).
// ---------------------------------------------------------------------------
#define NTILES (E_N / 128)

__global__ __launch_bounds__(512, 4) void k_edge_gcl(
    const int* __restrict__ srow, const int* __restrict__ scol,
    const char* __restrict__ PQ,
    const float* __restrict__ ea2, const float* __restrict__ w1c,
    const bf16* __restrict__ ew2T,
    const float* __restrict__ eb2, const float* __restrict__ aw,
    const float* __restrict__ ab, float* __restrict__ agg) {
    __shared__ __align__(16) bf16 Asl[128][136];   // A-tile; overlaid by FslT[128][40]
    __shared__ __align__(16) bf16 Bsl[128][136];   // persistent weight tile
    __shared__ int rows_s[2][128];
    __shared__ int cols_s[2][128];
    __shared__ float ra_s[2][128], aa_s[2][128];
    bf16(*FslT)[40] = (bf16(*)[40])Asl;            // [col][edge], stride 80B
    int tid = threadIdx.x;
    int lane = tid & 63, w = tid >> 6, q = lane >> 4, l15 = lane & 15;
    int j = (tid & 31) * 4;   // fixed column group per thread
    int eslot = tid >> 5;     // edge sub-slot (0..15)

    // stage B once
#pragma unroll
    for (int p = 0; p < 4; p++) {
        int e8 = (p * 512 + tid) * 8;
        int n = e8 >> 7, k = e8 & 127;
        *(bf16x8*)&Bsl[n][k] = *(const bf16x8*)&ew2T[n * 128 + k];
    }
    float4 w0r = *(const float4*)&w1c[j];
    float4 w1r = *(const float4*)&w1c[128 + j];
    float b2v[8], awv[8];
#pragma unroll
    for (int nt = 0; nt < 8; nt++) {
        b2v[nt] = eb2[nt * 16 + l15];
        awv[nt] = aw[nt * 16 + l15];
    }
    float ab0 = ab[0];

    // prologue: stage meta(t0) into buffer 0 (visible after first loop barrier)
    int t0 = blockIdx.x;
    if (tid < 128) {
        int e = t0 * 128 + tid;
        rows_s[0][tid] = srow[e];
        cols_s[0][tid] = scol[e];
        float2 rr = *(const float2*)&ea2[(size_t)e * 2];
        ra_s[0][tid] = rr.x;
        aa_s[0][tid] = rr.y;
    }

    int b = 0;
    for (int t = t0; t < NTILES; t += gridDim.x, b ^= 1) {
        int tn = t + gridDim.x;
        __syncthreads();   // B1: prev seg-reduce done; meta[b] visible
        // stage next tile's meta (overlaps with stage-A below)
        if (tn < NTILES && tid < 128) {
            int e = tn * 128 + tid;
            rows_s[b ^ 1][tid] = srow[e];
            cols_s[b ^ 1][tid] = scol[e];
            float2 rr = *(const float2*)&ea2[(size_t)e * 2];
            ra_s[b ^ 1][tid] = rr.x;
            aa_s[b ^ 1][tid] = rr.y;
        }
        // stage A: issue all 16 gathers, then compute
        bf16x4 pb[8];
        bf16x4 qb[8];
#pragma unroll
        for (int p = 0; p < 8; p++) {
            int el = p * 16 + eslot;
            int row = rows_s[b][el], col = cols_s[b][el];
            pb[p] = *(const bf16x4*)(PQ + (size_t)row * PQ_STRIDE + j * 2);
            qb[p] = *(const bf16x4*)(PQ + (size_t)col * PQ_STRIDE + 256 + j * 2);
        }
#pragma unroll
        for (int p = 0; p < 8; p++) {
            int el = p * 16 + eslot;
            float ra = ra_s[b][el], aa = aa_s[b][el];
            float zx = (float)pb[p][0] + (float)qb[p][0];
            float zy = (float)pb[p][1] + (float)qb[p][1];
            float zz = (float)pb[p][2] + (float)qb[p][2];
            float zw = (float)pb[p][3] + (float)qb[p][3];
            zx = fmaf(aa, w1r.x, fmaf(ra, w0r.x, zx));
            zy = fmaf(aa, w1r.y, fmaf(ra, w0r.y, zy));
            zz = fmaf(aa, w1r.z, fmaf(ra, w0r.z, zz));
            zw = fmaf(aa, w1r.w, fmaf(ra, w0r.w, zw));
            bf16x4 b4 = {(bf16)silu_f(zx), (bf16)silu_f(zy),
                         (bf16)silu_f(zz), (bf16)silu_f(zw)};
            *(bf16x4*)&Asl[el][j] = b4;
        }
        __syncthreads();   // B3: Asl ready
        f32x4 acc[8];
#pragma unroll
        for (int i = 0; i < 8; i++) acc[i] = (f32x4){0.f, 0.f, 0.f, 0.f};
        int ar = w * 16 + l15;
#pragma unroll
        for (int kt = 0; kt < 4; kt++) {
            bf16x8 a = *(const bf16x8*)&Asl[ar][kt * 32 + q * 8];
#pragma unroll
            for (int nt = 0; nt < 8; nt++) {
                bf16x8 bb = *(const bf16x8*)&Bsl[nt * 16 + l15][kt * 32 + q * 8];
                acc[nt] = __builtin_amdgcn_mfma_f32_16x16x32_bf16(a, bb, acc[nt], 0, 0, 0);
            }
        }
        // epilogue in regs: silu + attention dot
        float partial[4] = {0.f, 0.f, 0.f, 0.f};
#pragma unroll
        for (int nt = 0; nt < 8; nt++) {
#pragma unroll
            for (int reg = 0; reg < 4; reg++) {
                float mv = silu_f(acc[nt][reg] + b2v[nt]);
                acc[nt][reg] = mv;
                partial[reg] += mv * awv[nt];
            }
        }
        float scale[4];
#pragma unroll
        for (int reg = 0; reg < 4; reg++) {
            float s = partial[reg];
            s += __shfl_xor(s, 1, 16);
            s += __shfl_xor(s, 2, 16);
            s += __shfl_xor(s, 4, 16);
            s += __shfl_xor(s, 8, 16);
            scale[reg] = sigmoid_f(s + ab0) * 0.01f;
        }
        __syncthreads();   // B4: Asl MFMA reads done -> overlay FslT
#pragma unroll
        for (int reg = 0; reg < 4; reg++) {
            int er = w * 16 + q * 4 + reg;
            float sc = scale[reg];
#pragma unroll
            for (int nt = 0; nt < 8; nt++) {
                FslT[nt * 16 + l15][er] = (bf16)(acc[nt][reg] * sc);
            }
        }
        __syncthreads();   // B5: FslT ready
        // segmented reduction: vector-read this thread's 32 edge values
        int col = tid & 127, quarter = tid >> 7;
        int es = quarter * 32;
        bf16x8 f[4];
#pragma unroll
        for (int k2 = 0; k2 < 4; k2++) {
            f[k2] = *(const bf16x8*)&FslT[col][es + k2 * 8];
        }
        float sum = 0.f;
#pragma unroll
        for (int el2 = 0; el2 < 32; ++el2) {
            sum += (float)f[el2 >> 3][el2 & 7];
            int r = rows_s[b][es + el2];
            int nxt = (el2 < 31) ? rows_s[b][es + el2 + 1] : -1;
            if (r != nxt) {
                atomicAdd(&agg[(size_t)r * 128 + col], sum);
                sum = 0.f;
            }
        }
    }
}

// ---------------------------------------------------------------------------
// Persistent fused coord-update edge kernel (meta + cds double-buffered)
// ---------------------------------------------------------------------------
__global__ __launch_bounds__(512, 4) void k_edge_coord(
    const int* __restrict__ srow, const int* __restrict__ scol,
    const char* __restrict__ PQ,
    const float* __restrict__ ea2, const float* __restrict__ c1c,
    const bf16* __restrict__ cw2T,
    const float* __restrict__ cb2, const float* __restrict__ cw3,
    const float* __restrict__ cd, float* __restrict__ xagg) {
    __shared__ __align__(16) bf16 Asl[128][136];
    __shared__ __align__(16) bf16 Bsl[128][136];
    __shared__ int rows_s[2][128];
    __shared__ int cols_s[2][128];
    __shared__ float ra_s[2][128], aa_s[2][128];
    __shared__ float cds[2][384];
    __shared__ float Ssl[128];
    int tid = threadIdx.x;
    int lane = tid & 63, w = tid >> 6, q = lane >> 4, l15 = lane & 15;
    int j = (tid & 31) * 4;
    int eslot = tid >> 5;

#pragma unroll
    for (int p = 0; p < 4; p++) {
        int e8 = (p * 512 + tid) * 8;
        int n = e8 >> 7, k = e8 & 127;
        *(bf16x8*)&Bsl[n][k] = *(const bf16x8*)&cw2T[n * 128 + k];
    }
    float4 w0r = *(const float4*)&c1c[j];
    float4 w1r = *(const float4*)&c1c[128 + j];
    float b2v[8], w3v[8];
#pragma unroll
    for (int nt = 0; nt < 8; nt++) {
        b2v[nt] = cb2[nt * 16 + l15];
        w3v[nt] = cw3[nt * 16 + l15];
    }

    int t0 = blockIdx.x;
    if (tid < 128) {
        int e = t0 * 128 + tid;
        rows_s[0][tid] = srow[e];
        cols_s[0][tid] = scol[e];
        float2 rr = *(const float2*)&ea2[(size_t)e * 2];
        ra_s[0][tid] = rr.x;
        aa_s[0][tid] = rr.y;
    }
    if (tid < 384) cds[0][tid] = cd[(size_t)t0 * 384 + tid];

    int b = 0;
    for (int t = t0; t < NTILES; t += gridDim.x, b ^= 1) {
        int tn = t + gridDim.x;
        __syncthreads();   // B1
        if (tn < NTILES) {
            if (tid < 128) {
                int e = tn * 128 + tid;
                rows_s[b ^ 1][tid] = srow[e];
                cols_s[b ^ 1][tid] = scol[e];
                float2 rr = *(const float2*)&ea2[(size_t)e * 2];
                ra_s[b ^ 1][tid] = rr.x;
                aa_s[b ^ 1][tid] = rr.y;
            }
            if (tid < 384) cds[b ^ 1][tid] = cd[(size_t)tn * 384 + tid];
        }
        bf16x4 pb[8];
        bf16x4 qb[8];
#pragma unroll
        for (int p = 0; p < 8; p++) {
            int el = p * 16 + eslot;
            int row = rows_s[b][el], col = cols_s[b][el];
            pb[p] = *(const bf16x4*)(PQ + (size_t)row * PQ_STRIDE + j * 2);
            qb[p] = *(const bf16x4*)(PQ + (size_t)col * PQ_STRIDE + 256 + j * 2);
        }
#pragma unroll
        for (int p = 0; p < 8; p++) {
            int el = p * 16 + eslot;
            float ra = ra_s[b][el], aa = aa_s[b][el];
            float zx = (float)pb[p][0] + (float)qb[p][0];
            float zy = (float)pb[p][1] + (float)qb[p][1];
            float zz = (float)pb[p][2] + (float)qb[p][2];
            float zw = (float)pb[p][3] + (float)qb[p][3];
            zx = fmaf(aa, w1r.x, fmaf(ra, w0r.x, zx));
            zy = fmaf(aa, w1r.y, fmaf(ra, w0r.y, zy));
            zz = fmaf(aa, w1r.z, fmaf(ra, w0r.z, zz));
            zw = fmaf(aa, w1r.w, fmaf(ra, w0r.w, zw));
            bf16x4 b4 = {(bf16)silu_f(zx), (bf16)silu_f(zy),
                         (bf16)silu_f(zz), (bf16)silu_f(zw)};
            *(bf16x4*)&Asl[el][j] = b4;
        }
        __syncthreads();   // B3
        f32x4 acc[8];
#pragma unroll
        for (int i = 0; i < 8; i++) acc[i] = (f32x4){0.f, 0.f, 0.f, 0.f};
        int ar = w * 16 + l15;
#pragma unroll
        for (int kt = 0; kt < 4; kt++) {
            bf16x8 a = *(const bf16x8*)&Asl[ar][kt * 32 + q * 8];
#pragma unroll
            for (int nt = 0; nt < 8; nt++) {
                bf16x8 bb = *(const bf16x8*)&Bsl[nt * 16 + l15][kt * 32 + q * 8];
                acc[nt] = __builtin_amdgcn_mfma_f32_16x16x32_bf16(a, bb, acc[nt], 0, 0, 0);
            }
        }
        float partial[4] = {0.f, 0.f, 0.f, 0.f};
#pragma unroll
        for (int nt = 0; nt < 8; nt++) {
#pragma unroll
            for (int reg = 0; reg < 4; reg++) {
                float tv = silu_f(acc[nt][reg] + b2v[nt]);
                partial[reg] += tv * w3v[nt];
            }
        }
#pragma unroll
        for (int reg = 0; reg < 4; reg++) {
            float s = partial[reg];
            s += __shfl_xor(s, 1, 16);
            s += __shfl_xor(s, 2, 16);
            s += __shfl_xor(s, 4, 16);
            s += __shfl_xor(s, 8, 16);
            if (l15 == 0) Ssl[w * 16 + q * 4 + reg] = s * 0.01f;
        }
        __syncthreads();   // Ssl ready
        // segmented reduce of trans = cd*s over sorted-row runs (48 thr x 8)
        if (tid < 48) {
            int d = tid % 3, chunk = tid / 3;
            int es = chunk * 8, ee = es + 8;
            float sum = 0.f;
            for (int el = es; el < ee; ++el) {
                sum += cds[b][el * 3 + d] * Ssl[el];
                int r = rows_s[b][el];
                int nxt = (el + 1 < ee) ? rows_s[b][el + 1] : -1;
                if (r != nxt) {
                    atomicAdd(&xagg[(size_t)r * 3 + d], sum);
                    sum = 0.f;
                }
            }
        }
    }
}

__global__ void k_finalx(const float* __restrict__ x, const float* __restrict__ xagg,
                         float* __restrict__ outx) {
    int i = blockIdx.x * 256 + threadIdx.x;
    if (i < V_N * 3) outx[i] = x[i] + xagg[i];
}

// ---------------------------------------------------------------------------
extern "C" void kernel_launch(void* const* d_in, const int* in_sizes, int n_in,
                              void* d_out, int out_size, void* d_ws, size_t ws_size,
                              hipStream_t stream) {
    const float* h = (const float*)d_in[0];
    const float* x = (const float*)d_in[1];
    const int* ei = (const int*)d_in[2];
    const float* eattr = (const float*)d_in[3];
    const float* ew1 = (const float*)d_in[4];
    const float* eb1 = (const float*)d_in[5];
    const float* ew2 = (const float*)d_in[6];
    const float* eb2 = (const float*)d_in[7];
    const float* aw = (const float*)d_in[8];
    const float* ab = (const float*)d_in[9];
    const float* nw1 = (const float*)d_in[10];
    const float* nb1 = (const float*)d_in[11];
    const float* nw2 = (const float*)d_in[12];
    const float* nb2 = (const float*)d_in[13];
    const float* cw1 = (const float*)d_in[14];
    const float* cb1 = (const float*)d_in[15];
    const float* cw2 = (const float*)d_in[16];
    const float* cb2 = (const float*)d_in[17];
    const float* cw3 = (const float*)d_in[18];

    char* ws = (char*)d_ws;
    size_t off_b = 0;
    auto alloc = [&](size_t b) {
        size_t o = off_b;
        off_b += (b + 255) & ~(size_t)255;
        return o;
    };
    float* cd = (float*)(ws + alloc((size_t)E_N * 3 * 4));
    float* ea2 = (float*)(ws + alloc((size_t)E_N * 2 * 4));
    char* PQ = (char*)(ws + alloc((size_t)V_N * PQ_STRIDE));
    float* agg = (float*)(ws + alloc((size_t)V_N * 128 * 4));
    float* xagg = (float*)(ws + alloc((size_t)V_N * 3 * 4));
    bf16* projT = (bf16*)(ws + alloc(2 * 256 * 128 * 2));
    bf16* ew2T = (bf16*)(ws + alloc(2 * 128 * 128 * 2));
    bf16* nw1T = (bf16*)(ws + alloc(2 * 128 * 256 * 2));
    bf16* nw2T = (bf16*)(ws + alloc(2 * 128 * 128 * 2));
    bf16* cprojT = (bf16*)(ws + alloc(256 * 128 * 2));
    bf16* cw2T = (bf16*)(ws + alloc(128 * 128 * 2));
    float* biasPQ = (float*)(ws + alloc(2 * 256 * 4));
    float* biasCPQ = (float*)(ws + alloc(256 * 4));
    int* cnt = (int*)(ws + alloc((size_t)V_N * 4));
    int* offv = (int*)(ws + alloc((size_t)V_N * 4));
    int* srow = (int*)(ws + alloc((size_t)E_N * 4));
    int* scol = (int*)(ws + alloc((size_t)E_N * 4));
    int* perm = (int*)(ws + alloc((size_t)E_N * 4));

    float* outh = (float*)d_out;
    float* outx = outh + (size_t)V_N * 128;

    hipMemcpyAsync(outh, h, (size_t)V_N * 128 * 4, hipMemcpyDeviceToDevice, stream);
    k_weights<<<964, 256, 0, stream>>>(ew1, ew2, nw1, nw2, cw1, cw2, eb1, cb1,
                                       projT, ew2T, nw1T, nw2T, cprojT, cw2T,
                                       biasPQ, biasCPQ);
    // counting sort of edges by row
    hipMemsetAsync(cnt, 0, (size_t)V_N * 4, stream);
    k_hist<<<(E_N + 255) / 256, 256, 0, stream>>>(ei, cnt);
    k_scan<<<1, 1024, 0, stream>>>(cnt, offv);
    k_scatter<<<(E_N + 255) / 256, 256, 0, stream>>>(ei, offv, srow, scol, perm);
    k_edgeprep2<<<(E_N + 255) / 256, 256, 0, stream>>>(perm, srow, scol, x, eattr, cd, ea2);
    hipMemsetAsync(xagg, 0, (size_t)V_N * 3 * 4, stream);
    hipMemsetAsync(agg, 0, (size_t)V_N * 128 * 4, stream);

    int mblocks = (V_N + 63) / 64;
    // layer 0: standalone projection (bias-folded)
    dim3 gproj(mblocks, 2);
    k_node_gemm<<<gproj, 256, 0, stream>>>(outh, nullptr, projT, biasPQ, nullptr,
                                           (float*)PQ, V_N, 128, 256, 0, 1);
    k_edge_gcl<<<512, 512, 0, stream>>>(
        srow, scol, PQ, ea2, ew1 + 256 * 128,
        ew2T, eb2, aw, ab, agg);
    // node MLP 0 (zeroes agg in place) + fused projection for layer 1
    k_node_mlp<<<mblocks, 256, 0, stream>>>(agg, nw1T, nb1, nw2T, nb2, outh, V_N, 1,
                                            projT + 256 * 128, biasPQ + 256, PQ);
    k_edge_gcl<<<512, 512, 0, stream>>>(
        srow, scol, PQ, ea2, ew1 + (size_t)1 * 258 * 128 + 256 * 128,
        ew2T + 128 * 128, eb2 + 128, aw + 128, ab + 1, agg);
    // node MLP 1 + fused coord projection
    k_node_mlp<<<mblocks, 256, 0, stream>>>(agg, nw1T + 128 * 256, nb1 + 128,
                                            nw2T + 128 * 128, nb2 + 128, outh, V_N, 0,
                                            cprojT, biasCPQ, PQ);
    k_edge_coord<<<512, 512, 0, stream>>>(srow, scol, PQ, ea2, cw1 + 256 * 128,
                                          cw2T, cb2, cw3, cd, xagg);
    k_finalx<<<(V_N * 3 + 255) / 256, 256, 0, stream>>>(x, xagg, outx);
}